// Round 4
// baseline (202.057 us; speedup 1.0000x reference)
//
#include <hip/hip_runtime.h>
#include <math.h>
#include <stdint.h>

#define B_ 4
#define S_ 1024
#define F_ 512    // W*DIM = HEADS*HD
#define HD 128

typedef __attribute__((ext_vector_type(8))) short short8;
typedef __attribute__((ext_vector_type(4))) float f32x4;
typedef __attribute__((ext_vector_type(4))) unsigned int u32x4;
typedef __attribute__((ext_vector_type(2))) unsigned int u32x2;

__device__ __forceinline__ unsigned short f2bf(float f) {
    unsigned int u = __float_as_uint(f);
    u = (u + 0x7FFFu + ((u >> 16) & 1u)) >> 16;
    return (unsigned short)u;
}
__device__ __forceinline__ float bf2f(unsigned int s) {
    return __uint_as_float(s << 16);
}
// split-bf16 hi/lo pack of 8 floats -> two bf16x8 fragments
__device__ __forceinline__ void pack_hilo(const float* v, u32x4& hi, u32x4& lo) {
    #pragma unroll
    for (int p = 0; p < 4; ++p) {
        unsigned int h0 = f2bf(v[2 * p]), h1 = f2bf(v[2 * p + 1]);
        float l0 = v[2 * p] - bf2f(h0), l1 = v[2 * p + 1] - bf2f(h1);
        hi[p] = h0 | (h1 << 16);
        lo[p] = (unsigned int)f2bf(l0) | ((unsigned int)f2bf(l1) << 16);
    }
}

// ---------------------------------------------------------------------------
// K1: QKV projection as MFMA GEMM (split-bf16).  Also computes the strength
// vector per block (redundant, cheap) and scatter-stores V directly in the
// transposed yvT[bh][d][t] layout (replaces the old k_sv and k_vtrans).
// ---------------------------------------------------------------------------
__global__ __launch_bounds__(256) void k_qkv(
    const float* __restrict__ x, const float* __restrict__ strength,
    const int* __restrict__ embed_id,
    const float* __restrict__ qw, const float* __restrict__ kw,
    const float* __restrict__ vw,
    const float* __restrict__ str_w, const float* __restrict__ str_b,
    unsigned short* __restrict__ yq, unsigned short* __restrict__ yk,
    unsigned short* __restrict__ yvT)
{
    __shared__ float part_s[4][64];
    __shared__ float sv_s[64];
    const int tid  = threadIdx.x;
    const int wv   = tid >> 6;
    const int lane = tid & 63;
    const int quad = lane >> 4;
    const int l15  = lane & 15;

    // strength projection (per-block redundant; str_w is L2/L3-resident)
    {
        const int c = lane;
        const float* wrow = str_w + c * 512 + wv * 128;
        const float* st   = strength + wv * 128;
        float acc = 0.f;
        #pragma unroll
        for (int j4 = 0; j4 < 32; ++j4) {
            f32x4 wv4 = *(const f32x4*)(wrow + j4 * 4);
            f32x4 s4  = *(const f32x4*)(st + j4 * 4);
            acc += wv4[0] * s4[0] + wv4[1] * s4[1] + wv4[2] * s4[2] + wv4[3] * s4[3];
        }
        part_s[wv][c] = acc;
    }
    __syncthreads();
    if (wv == 0)
        sv_s[lane] = part_s[0][lane] + part_s[1][lane] + part_s[2][lane]
                   + part_s[3][lane] + str_b[lane];
    __syncthreads();

    const int r0   = blockIdx.x * 64 + wv * 16;   // 16 rows for this wave
    const int b    = r0 >> 13;
    const int rloc = (r0 & 8191) + l15;           // (s,w) flat within batch
    const float* xb = x + (size_t)b * 524288;
    const int id = embed_id[0];

    // B fragments (x^T), hi/lo split.  B[n=l15][k=quad*8+j]
    u32x4 bhi[2], blo[2];
    #pragma unroll
    for (int kc = 0; kc < 2; ++kc) {
        float xv[8];
        #pragma unroll
        for (int j = 0; j < 8; ++j)
            xv[j] = xb[(kc * 32 + quad * 8 + j) * 8192 + rloc];
        pack_hilo(xv, bhi[kc], blo[kc]);
    }

    f32x4 svr[4];
    #pragma unroll
    for (int mt = 0; mt < 4; ++mt)
        svr[mt] = *(const f32x4*)(&sv_s[mt * 16 + quad * 4]);

    const float SCALE = 0.08838834764831845f;  // 1/sqrt(128)

    // V scatter-store geometry (row -> (b,s,w) -> yvT address)
    const int row_g  = r0 + l15;
    const int s_idx  = (row_g >> 3) & 1023;
    const int w_idx  = row_g & 7;
    const int bh_v   = b * 4 + (w_idx >> 1);
    unsigned short* vtb = yvT + ((size_t)(bh_v * HD + (w_idx & 1) * 64)) * S_ + s_idx;

    for (int mat = 0; mat < 3; ++mat) {
        const float* em = (mat == 0 ? qw : mat == 1 ? kw : vw) + id * 4096;
        u32x4 ahi[4][2], alo[4][2];
        #pragma unroll
        for (int mt = 0; mt < 4; ++mt)
            #pragma unroll
            for (int kc = 0; kc < 2; ++kc) {
                const float* src = em + (mt * 16 + l15) * 64 + kc * 32 + quad * 8;
                f32x4 e0 = *(const f32x4*)src;
                f32x4 e1 = *(const f32x4*)(src + 4);
                float ev[8] = {e0[0], e0[1], e0[2], e0[3], e1[0], e1[1], e1[2], e1[3]};
                pack_hilo(ev, ahi[mt][kc], alo[mt][kc]);
            }

        f32x4 acc[4] = {};
        #pragma unroll
        for (int kc = 0; kc < 2; ++kc)
            #pragma unroll
            for (int mt = 0; mt < 4; ++mt) {
                acc[mt] = __builtin_amdgcn_mfma_f32_16x16x32_bf16(
                    __builtin_bit_cast(short8, ahi[mt][kc]),
                    __builtin_bit_cast(short8, bhi[kc]), acc[mt], 0, 0, 0);
                acc[mt] = __builtin_amdgcn_mfma_f32_16x16x32_bf16(
                    __builtin_bit_cast(short8, ahi[mt][kc]),
                    __builtin_bit_cast(short8, blo[kc]), acc[mt], 0, 0, 0);
                acc[mt] = __builtin_amdgcn_mfma_f32_16x16x32_bf16(
                    __builtin_bit_cast(short8, alo[mt][kc]),
                    __builtin_bit_cast(short8, bhi[kc]), acc[mt], 0, 0, 0);
            }

        if (mat < 2) {
            unsigned short* y = (mat == 0 ? yq : yk);
            #pragma unroll
            for (int mt = 0; mt < 4; ++mt) {
                float v0 = acc[mt][0] + svr[mt][0];
                float v1 = acc[mt][1] + svr[mt][1];
                float v2 = acc[mt][2] + svr[mt][2];
                float v3 = acc[mt][3] + svr[mt][3];
                if (mat == 0) { v0 *= SCALE; v1 *= SCALE; v2 *= SCALE; v3 *= SCALE; }
                u32x2 pk;
                pk[0] = (unsigned int)f2bf(v0) | ((unsigned int)f2bf(v1) << 16);
                pk[1] = (unsigned int)f2bf(v2) | ((unsigned int)f2bf(v3) << 16);
                *(u32x2*)(y + (size_t)row_g * 64 + mt * 16 + quad * 4) = pk;
            }
        } else {
            // V: straight to transposed layout  yvT[bh*128 + (w&1)*64 + c][s]
            #pragma unroll
            for (int mt = 0; mt < 4; ++mt)
                #pragma unroll
                for (int rr = 0; rr < 4; ++rr) {
                    const int c = mt * 16 + quad * 4 + rr;
                    vtb[(size_t)c * S_] = f2bf(acc[mt][rr] + svr[mt][rr]);
                }
        }
    }
}

// ---------------------------------------------------------------------------
// K3: pos-attention collapsed branch.  pos_attn rows are s-independent =>
// vbar[bh][d] = sum_t softmax_t(-A[t]) * V[t][d].  One block per bh.
// ---------------------------------------------------------------------------
__global__ __launch_bounds__(256) void k_vbar(
    const unsigned short* __restrict__ yvT, const float* __restrict__ pos,
    const float* __restrict__ pw1, const float* __restrict__ pb1,
    const float* __restrict__ pw2, const float* __restrict__ pb2,
    const float* __restrict__ head_w, float* __restrict__ vbar_g)
{
    __shared__ float p_s[1024];
    __shared__ float red_s[4];
    __shared__ float stat_s;
    const int tid = threadIdx.x, wv = tid >> 6;
    const int bh = blockIdx.x, b = bh >> 2, h = bh & 3;

    float w1_[9], b1_[3], w2_[24], b2_[8], hw_[8];
    #pragma unroll
    for (int i = 0; i < 9; ++i)  w1_[i] = pw1[i];
    #pragma unroll
    for (int i = 0; i < 3; ++i)  b1_[i] = pb1[i];
    #pragma unroll
    for (int i = 0; i < 24; ++i) w2_[i] = pw2[i];
    #pragma unroll
    for (int i = 0; i < 8; ++i)  b2_[i] = pb2[i];
    #pragma unroll
    for (int i = 0; i < 8; ++i)  hw_[i] = head_w[h * 8 + i];

    float lmax = -INFINITY;
    #pragma unroll
    for (int k = 0; k < 4; ++k) {
        const int t = k * 256 + tid;
        float p0 = pos[(b * S_ + t) * 3 + 0];
        float p1 = pos[(b * S_ + t) * 3 + 1];
        float p2 = pos[(b * S_ + t) * 3 + 2];
        float h0 = fmaxf(0.f, p0 * w1_[0] + p1 * w1_[1] + p2 * w1_[2] + b1_[0]);
        float h1 = fmaxf(0.f, p0 * w1_[3] + p1 * w1_[4] + p2 * w1_[5] + b1_[1]);
        float h2 = fmaxf(0.f, p0 * w1_[6] + p1 * w1_[7] + p2 * w1_[8] + b1_[2]);
        float A = 0.f;
        #pragma unroll
        for (int o8 = 0; o8 < 8; ++o8) {
            float ph = h0 * w2_[o8 * 3] + h1 * w2_[o8 * 3 + 1] + h2 * w2_[o8 * 3 + 2] + b2_[o8];
            A += ph * hw_[o8];
        }
        p_s[t] = -A;
        lmax = fmaxf(lmax, -A);
    }
    #pragma unroll
    for (int off = 1; off < 64; off <<= 1)
        lmax = fmaxf(lmax, __shfl_xor(lmax, off));
    if ((tid & 63) == 0) red_s[wv] = lmax;
    __syncthreads();
    const float bmax = fmaxf(fmaxf(red_s[0], red_s[1]), fmaxf(red_s[2], red_s[3]));
    __syncthreads();
    float lsum = 0.f;
    #pragma unroll
    for (int k = 0; k < 4; ++k) {
        const int t = k * 256 + tid;
        float e = __expf(p_s[t] - bmax);
        p_s[t] = e;
        lsum += e;
    }
    #pragma unroll
    for (int off = 1; off < 64; off <<= 1)
        lsum += __shfl_xor(lsum, off);
    if ((tid & 63) == 0) red_s[wv] = lsum;
    __syncthreads();
    if (tid == 0) stat_s = 1.f / (red_s[0] + red_s[1] + red_s[2] + red_s[3]);
    __syncthreads();
    const float inv = stat_s;

    const int d = tid >> 1, th = (tid & 1) * 512;
    const unsigned short* vrow = yvT + (size_t)(bh * HD + d) * S_ + th;
    float acc = 0.f;
    #pragma unroll 8
    for (int i = 0; i < 64; ++i) {
        u32x4 v = *(const u32x4*)(vrow + i * 8);
        const float* pp = p_s + th + i * 8;
        acc += pp[0] * bf2f(v[0] & 0xFFFFu) + pp[1] * bf2f(v[0] >> 16)
             + pp[2] * bf2f(v[1] & 0xFFFFu) + pp[3] * bf2f(v[1] >> 16)
             + pp[4] * bf2f(v[2] & 0xFFFFu) + pp[5] * bf2f(v[2] >> 16)
             + pp[6] * bf2f(v[3] & 0xFFFFu) + pp[7] * bf2f(v[3] >> 16);
    }
    acc += __shfl_xor(acc, 1);
    if ((tid & 1) == 0) vbar_g[bh * HD + d] = acc * inv;
}

// ---------------------------------------------------------------------------
// K4: flash attention, split-S.  Block = 4 waves = 4 chunks of 256 t for the
// same (bh, 16-row q-tile); grid 1024x256 -> 4 waves/SIMD.
// S^T trick: mfma(A=K, B=Q) puts q-row on l15 => softmax stats are per-lane
// scalars, O-rescale (PV^T D-layout also has col=q-row) needs no broadcast.
// P C-layout -> PV B-fragment via 4 __shfl (quad permute), zero barriers in
// the main loop.  Chunk partials (o, m, l) combined through LDS at the end.
// ---------------------------------------------------------------------------
__global__ __launch_bounds__(256, 4) void k_attn(
    const unsigned short* __restrict__ yq, const unsigned short* __restrict__ yk,
    const unsigned short* __restrict__ yvT, const float* __restrict__ vbar_g,
    const float* __restrict__ gate, float* __restrict__ out)
{
    __shared__ __align__(16) float acc_s[4][16 * 132];   // 33792 B
    __shared__ float mch_s[4][16], lch_s[4][16];

    const int tid  = threadIdx.x;
    const int w    = tid >> 6;        // chunk index
    const int lane = tid & 63;
    const int quad = lane >> 4;
    const int l15  = lane & 15;
    const int bh = blockIdx.x & 15, qt = blockIdx.x >> 4;
    const int b = bh >> 2, h = bh & 3;
    const int s0 = qt * 16;

    // Q fragments (B-operand of S^T = K Q^T), register-resident
    u32x4 qf[4];
    #pragma unroll
    for (int kc = 0; kc < 4; ++kc)
        qf[kc] = *(const u32x4*)(yq +
            (size_t)(b * S_ + s0 + l15) * F_ + h * HD + kc * 32 + quad * 8);

    f32x4 o[8] = {};
    float m_ = -INFINITY, l_ = 0.f;
    const int srcA = ((quad & 1) << 5) + l15;
    const unsigned short* ykb = yk + (size_t)(b * S_) * F_ + h * HD;
    const unsigned short* yvb = yvT + (size_t)(bh * HD) * S_;

    for (int it = 0; it < 8; ++it) {
        const int t0 = w * 256 + it * 32;

        // ---- S^T = K Q^T over two 16-t subtiles ----
        u32x4 kf0[4], kf1[4];
        #pragma unroll
        for (int kc = 0; kc < 4; ++kc)
            kf0[kc] = *(const u32x4*)(ykb + (size_t)(t0 + l15) * F_ + kc * 32 + quad * 8);
        #pragma unroll
        for (int kc = 0; kc < 4; ++kc)
            kf1[kc] = *(const u32x4*)(ykb + (size_t)(t0 + 16 + l15) * F_ + kc * 32 + quad * 8);
        f32x4 sa0 = {}, sa1 = {};
        #pragma unroll
        for (int kc = 0; kc < 4; ++kc)
            sa0 = __builtin_amdgcn_mfma_f32_16x16x32_bf16(
                __builtin_bit_cast(short8, kf0[kc]),
                __builtin_bit_cast(short8, qf[kc]), sa0, 0, 0, 0);
        #pragma unroll
        for (int kc = 0; kc < 4; ++kc)
            sa1 = __builtin_amdgcn_mfma_f32_16x16x32_bf16(
                __builtin_bit_cast(short8, kf1[kc]),
                __builtin_bit_cast(short8, qf[kc]), sa1, 0, 0, 0);
        // lane holds S[q=l15][t0+quad*4+r] (sa0) and S[q=l15][t0+16+quad*4+r] (sa1)

        // ---- online softmax, per-lane scalar stats (row = l15) ----
        float mx = fmaxf(fmaxf(fmaxf(sa0[0], sa0[1]), fmaxf(sa0[2], sa0[3])),
                         fmaxf(fmaxf(sa1[0], sa1[1]), fmaxf(sa1[2], sa1[3])));
        mx = fmaxf(mx, __shfl_xor(mx, 16));
        mx = fmaxf(mx, __shfl_xor(mx, 32));
        const float mn = fmaxf(m_, mx);
        const float alpha = __expf(m_ - mn);
        m_ = mn;
        float p0[4], p1[4];
        float sum = 0.f;
        #pragma unroll
        for (int r = 0; r < 4; ++r) {
            p0[r] = __expf(sa0[r] - mn);
            p1[r] = __expf(sa1[r] - mn);
            sum += p0[r] + p1[r];
        }
        sum += __shfl_xor(sum, 16);
        sum += __shfl_xor(sum, 32);
        l_ = l_ * alpha + sum;
        #pragma unroll
        for (int dt = 0; dt < 8; ++dt) {
            o[dt][0] *= alpha; o[dt][1] *= alpha; o[dt][2] *= alpha; o[dt][3] *= alpha;
        }

        // ---- P (C-layout) -> B-fragment of PV^T via quad-permute shuffles ----
        unsigned int pk00 = (unsigned int)f2bf(p0[0]) | ((unsigned int)f2bf(p0[1]) << 16);
        unsigned int pk01 = (unsigned int)f2bf(p0[2]) | ((unsigned int)f2bf(p0[3]) << 16);
        unsigned int pk10 = (unsigned int)f2bf(p1[0]) | ((unsigned int)f2bf(p1[1]) << 16);
        unsigned int pk11 = (unsigned int)f2bf(p1[2]) | ((unsigned int)f2bf(p1[3]) << 16);
        unsigned int sel0 = (quad < 2) ? pk00 : pk10;
        unsigned int sel1 = (quad < 2) ? pk01 : pk11;
        u32x4 pf;
        pf[0] = (unsigned int)__shfl((int)sel0, srcA);
        pf[1] = (unsigned int)__shfl((int)sel1, srcA);
        pf[2] = (unsigned int)__shfl((int)sel0, srcA + 16);
        pf[3] = (unsigned int)__shfl((int)sel1, srcA + 16);

        // ---- O^T += V^T P^T ----
        #pragma unroll
        for (int dt = 0; dt < 8; ++dt) {
            u32x4 vf = *(const u32x4*)(yvb + (size_t)(dt * 16 + l15) * S_ + t0 + quad * 8);
            o[dt] = __builtin_amdgcn_mfma_f32_16x16x32_bf16(
                __builtin_bit_cast(short8, vf),
                __builtin_bit_cast(short8, pf), o[dt], 0, 0, 0);
        }
    }

    // ---- write chunk partials to LDS ----
    float* my = acc_s[w];
    #pragma unroll
    for (int dt = 0; dt < 8; ++dt)
        *(f32x4*)&my[l15 * 132 + dt * 16 + quad * 4] = o[dt];
    if (quad == 0) { mch_s[w][l15] = m_; lch_s[w][l15] = l_; }
    __syncthreads();

    // ---- combine 4 chunks + gate/vbar, write Y ----
    const int row = tid >> 4, d0 = (tid & 15) * 8;
    float M = fmaxf(fmaxf(mch_s[0][row], mch_s[1][row]),
                    fmaxf(mch_s[2][row], mch_s[3][row]));
    float L = 0.f;
    float y0[4] = {}, y1[4] = {};
    #pragma unroll
    for (int c = 0; c < 4; ++c) {
        float e = __expf(mch_s[c][row] - M);
        L += e * lch_s[c][row];
        f32x4 a0 = *(const f32x4*)&acc_s[c][row * 132 + d0];
        f32x4 a1 = *(const f32x4*)&acc_s[c][row * 132 + d0 + 4];
        #pragma unroll
        for (int j = 0; j < 4; ++j) { y0[j] += e * a0[j]; y1[j] += e * a1[j]; }
    }
    const float gf = 1.f / (1.f + __expf(-gate[h]));
    const float cf = (1.f - gf) / L;
    f32x4 vb0 = *(const f32x4*)(vbar_g + bh * HD + d0);
    f32x4 vb1 = *(const f32x4*)(vbar_g + bh * HD + d0 + 4);
    f32x4 r0v, r1v;
    #pragma unroll
    for (int j = 0; j < 4; ++j) {
        r0v[j] = cf * y0[j] + gf * vb0[j];
        r1v[j] = cf * y1[j] + gf * vb1[j];
    }
    float* op = out + (size_t)(b * S_ + s0 + row) * F_ + h * HD + d0;
    *(f32x4*)op = r0v;
    *(f32x4*)(op + 4) = r1v;
}

// ---------------------------------------------------------------------------
// K5: output projection as MFMA (split-bf16), in-place on d_out.
// Wave owns 16 rows exclusively: loads before stores => in-place safe.
// ---------------------------------------------------------------------------
__global__ __launch_bounds__(256) void k_oproj(
    float* __restrict__ out, const float* __restrict__ ow,
    const float* __restrict__ ob)
{
    const int tid  = threadIdx.x;
    const int wv   = tid >> 6;
    const int lane = tid & 63;
    const int quad = lane >> 4;
    const int l15  = lane & 15;
    const int r0   = blockIdx.x * 64 + wv * 16;

    // B fragments from Y rows (hi/lo split)
    u32x4 bhi[2], blo[2];
    #pragma unroll
    for (int kc = 0; kc < 2; ++kc) {
        const float* src = out + (size_t)(r0 + l15) * 64 + kc * 32 + quad * 8;
        f32x4 y0 = *(const f32x4*)src;
        f32x4 y1 = *(const f32x4*)(src + 4);
        float yv8[8] = {y0[0], y0[1], y0[2], y0[3], y1[0], y1[1], y1[2], y1[3]};
        pack_hilo(yv8, bhi[kc], blo[kc]);
    }
    // A fragments from out_w
    u32x4 ahi[4][2], alo[4][2];
    #pragma unroll
    for (int mt = 0; mt < 4; ++mt)
        #pragma unroll
        for (int kc = 0; kc < 2; ++kc) {
            const float* src = ow + (mt * 16 + l15) * 64 + kc * 32 + quad * 8;
            f32x4 e0 = *(const f32x4*)src;
            f32x4 e1 = *(const f32x4*)(src + 4);
            float ev[8] = {e0[0], e0[1], e0[2], e0[3], e1[0], e1[1], e1[2], e1[3]};
            pack_hilo(ev, ahi[mt][kc], alo[mt][kc]);
        }

    f32x4 acc[4] = {};
    #pragma unroll
    for (int kc = 0; kc < 2; ++kc)
        #pragma unroll
        for (int mt = 0; mt < 4; ++mt) {
            acc[mt] = __builtin_amdgcn_mfma_f32_16x16x32_bf16(
                __builtin_bit_cast(short8, ahi[mt][kc]),
                __builtin_bit_cast(short8, bhi[kc]), acc[mt], 0, 0, 0);
            acc[mt] = __builtin_amdgcn_mfma_f32_16x16x32_bf16(
                __builtin_bit_cast(short8, ahi[mt][kc]),
                __builtin_bit_cast(short8, blo[kc]), acc[mt], 0, 0, 0);
            acc[mt] = __builtin_amdgcn_mfma_f32_16x16x32_bf16(
                __builtin_bit_cast(short8, alo[mt][kc]),
                __builtin_bit_cast(short8, bhi[kc]), acc[mt], 0, 0, 0);
        }

    #pragma unroll
    for (int mt = 0; mt < 4; ++mt) {
        f32x4 bias = *(const f32x4*)(ob + mt * 16 + quad * 4);
        f32x4 v = acc[mt] + bias;
        *(f32x4*)(out + (size_t)(r0 + l15) * 64 + mt * 16 + quad * 4) = v;
    }
}

extern "C" void kernel_launch(void* const* d_in, const int* in_sizes, int n_in,
                              void* d_out, int out_size, void* d_ws, size_t ws_size,
                              hipStream_t stream) {
    (void)in_sizes; (void)n_in; (void)out_size; (void)ws_size;
    const float* x        = (const float*)d_in[0];
    const float* pos      = (const float*)d_in[1];
    const float* strength = (const float*)d_in[2];
    const int*   embed_id = (const int*)d_in[3];
    const float* qw       = (const float*)d_in[4];
    const float* kw       = (const float*)d_in[5];
    const float* vw       = (const float*)d_in[6];
    const float* pw1      = (const float*)d_in[7];
    const float* pb1      = (const float*)d_in[8];
    const float* pw2      = (const float*)d_in[9];
    const float* pb2      = (const float*)d_in[10];
    const float* head_w   = (const float*)d_in[11];
    const float* gate     = (const float*)d_in[13];
    const float* out_w    = (const float*)d_in[14];
    const float* out_b    = (const float*)d_in[15];
    const float* str_w    = (const float*)d_in[16];
    const float* str_b    = (const float*)d_in[17];
    float* out = (float*)d_out;

    unsigned short* yq  = (unsigned short*)d_ws;           // 4 MiB
    unsigned short* yk  = yq + 2097152;                    // 4 MiB
    unsigned short* yvT = yk + 2097152;                    // 4 MiB
    float*          vbar_g = (float*)(yvT + 2097152);      // 8 KiB

    k_qkv<<<512, 256, 0, stream>>>(x, strength, embed_id, qw, kw, vw,
                                   str_w, str_b, yq, yk, yvT);
    k_vbar<<<16, 256, 0, stream>>>(yvT, pos, pw1, pb1, pw2, pb2, head_w, vbar_g);
    k_attn<<<1024, 256, 0, stream>>>(yq, yk, yvT, vbar_g, gate, out);
    k_oproj<<<512, 256, 0, stream>>>(out, out_w, out_b);
}

// Round 5
// 192.763 us; speedup vs baseline: 1.0482x; 1.0482x over previous
//
#include <hip/hip_runtime.h>
#include <math.h>
#include <stdint.h>

#define B_ 4
#define S_ 1024
#define F_ 512    // W*DIM = HEADS*HD
#define HD 128
#define SOFT_C 4.0f   // fixed exp-centering; |S| << 88 so no running max needed

typedef __attribute__((ext_vector_type(8))) short short8;
typedef __attribute__((ext_vector_type(4))) float f32x4;
typedef __attribute__((ext_vector_type(4))) unsigned int u32x4;
typedef __attribute__((ext_vector_type(2))) unsigned int u32x2;

__device__ __forceinline__ unsigned short f2bf(float f) {
    unsigned int u = __float_as_uint(f);
    u = (u + 0x7FFFu + ((u >> 16) & 1u)) >> 16;
    return (unsigned short)u;
}
__device__ __forceinline__ float bf2f(unsigned int s) {
    return __uint_as_float(s << 16);
}
__device__ __forceinline__ void pack_hilo(const float* v, u32x4& hi, u32x4& lo) {
    #pragma unroll
    for (int p = 0; p < 4; ++p) {
        unsigned int h0 = f2bf(v[2 * p]), h1 = f2bf(v[2 * p + 1]);
        float l0 = v[2 * p] - bf2f(h0), l1 = v[2 * p + 1] - bf2f(h1);
        hi[p] = h0 | (h1 << 16);
        lo[p] = (unsigned int)f2bf(l0) | ((unsigned int)f2bf(l1) << 16);
    }
}

// ---------------------------------------------------------------------------
// K0 k_prep: blk 0-3: pack {qw*scale, kw, vw, ow} -> bf16 hi/lo arrays.
//            blk 4-7: normalized pos-softmax p[b][h][t] (no-max exp).
//            blk 8  : strength vector sv / svq(=sv*scale).
// ---------------------------------------------------------------------------
__global__ __launch_bounds__(256) void k_prep(
    const int* __restrict__ embed_id,
    const float* __restrict__ qw, const float* __restrict__ kw,
    const float* __restrict__ vw, const float* __restrict__ ow,
    const float* __restrict__ pos,
    const float* __restrict__ pw1, const float* __restrict__ pb1,
    const float* __restrict__ pw2, const float* __restrict__ pb2,
    const float* __restrict__ head_w,
    const float* __restrict__ strength, const float* __restrict__ str_w,
    const float* __restrict__ str_b,
    unsigned short* __restrict__ packs,   // 8 x 4096 shorts: qh,ql,kh,kl,vh,vl,oh,ol
    float* __restrict__ sv, float* __restrict__ svq,
    float* __restrict__ p_g)
{
    __shared__ float red_s[4][4];
    __shared__ float inv_s[4];
    const int blk = blockIdx.x, tid = threadIdx.x;
    const float SCALE = 0.08838834764831845f;

    if (blk < 4) {
        const int id = embed_id[0];
        const float* src = (blk == 0 ? qw + id * 4096 : blk == 1 ? kw + id * 4096
                            : blk == 2 ? vw + id * 4096 : ow);
        const float scale = (blk == 0) ? SCALE : 1.0f;
        unsigned short* hi = packs + blk * 8192;
        unsigned short* lo = hi + 4096;
        for (int i = tid; i < 4096; i += 256) {
            float v = src[i] * scale;
            unsigned short h = f2bf(v);
            hi[i] = h;
            lo[i] = f2bf(v - bf2f(h));
        }
    } else if (blk < 8) {
        const int b = blk - 4;
        const int wv = tid >> 6;
        float w1_[9], b1_[3], w2_[24], b2_[8], hw_[32];
        #pragma unroll
        for (int i = 0; i < 9; ++i)  w1_[i] = pw1[i];
        #pragma unroll
        for (int i = 0; i < 3; ++i)  b1_[i] = pb1[i];
        #pragma unroll
        for (int i = 0; i < 24; ++i) w2_[i] = pw2[i];
        #pragma unroll
        for (int i = 0; i < 8; ++i)  b2_[i] = pb2[i];
        #pragma unroll
        for (int i = 0; i < 32; ++i) hw_[i] = head_w[i];

        float ev[4][4];
        float ps[4] = {0.f, 0.f, 0.f, 0.f};
        #pragma unroll
        for (int k = 0; k < 4; ++k) {
            const int t = k * 256 + tid;
            float p0 = pos[(b * S_ + t) * 3 + 0];
            float p1 = pos[(b * S_ + t) * 3 + 1];
            float p2 = pos[(b * S_ + t) * 3 + 2];
            float h0 = fmaxf(0.f, p0 * w1_[0] + p1 * w1_[1] + p2 * w1_[2] + b1_[0]);
            float h1 = fmaxf(0.f, p0 * w1_[3] + p1 * w1_[4] + p2 * w1_[5] + b1_[1]);
            float h2 = fmaxf(0.f, p0 * w1_[6] + p1 * w1_[7] + p2 * w1_[8] + b1_[2]);
            float ph[8];
            #pragma unroll
            for (int o8 = 0; o8 < 8; ++o8)
                ph[o8] = h0 * w2_[o8 * 3] + h1 * w2_[o8 * 3 + 1] + h2 * w2_[o8 * 3 + 2] + b2_[o8];
            #pragma unroll
            for (int h = 0; h < 4; ++h) {
                float A = 0.f;
                #pragma unroll
                for (int o8 = 0; o8 < 8; ++o8) A += ph[o8] * hw_[h * 8 + o8];
                ev[k][h] = __expf(-A - 1.0f);
                ps[h] += ev[k][h];
            }
        }
        #pragma unroll
        for (int h = 0; h < 4; ++h)
            #pragma unroll
            for (int off = 1; off < 64; off <<= 1)
                ps[h] += __shfl_xor(ps[h], off);
        if ((tid & 63) == 0)
            #pragma unroll
            for (int h = 0; h < 4; ++h) red_s[wv][h] = ps[h];
        __syncthreads();
        if (tid < 4)
            inv_s[tid] = 1.f / (red_s[0][tid] + red_s[1][tid] + red_s[2][tid] + red_s[3][tid]);
        __syncthreads();
        #pragma unroll
        for (int k = 0; k < 4; ++k)
            #pragma unroll
            for (int h = 0; h < 4; ++h)
                p_g[(b * 4 + h) * S_ + k * 256 + tid] = ev[k][h] * inv_s[h];
    } else {
        // strength projection
        __shared__ float part_s[4][64];
        const int c = tid & 63, pr = tid >> 6;
        const float* wrow = str_w + c * 512 + pr * 128;
        const float* st   = strength + pr * 128;
        float acc = 0.f;
        #pragma unroll
        for (int j4 = 0; j4 < 32; ++j4) {
            f32x4 wv4 = *(const f32x4*)(wrow + j4 * 4);
            f32x4 s4  = *(const f32x4*)(st + j4 * 4);
            acc += wv4[0] * s4[0] + wv4[1] * s4[1] + wv4[2] * s4[2] + wv4[3] * s4[3];
        }
        part_s[pr][c] = acc;
        __syncthreads();
        if (tid < 64) {
            float v = part_s[0][tid] + part_s[1][tid] + part_s[2][tid]
                    + part_s[3][tid] + str_b[tid];
            sv[tid] = v;
            svq[tid] = v * SCALE;
        }
    }
}

// ---------------------------------------------------------------------------
// K1 k_qkv: blk<512: QKV MFMA GEMM with PREPACKED bf16 hi/lo emb (no fp32
// emb reload / repack per wave).  V scatter-stored transposed to yvT.
//           blk>=512 (256 blocks): xbar[b][w][c] = sum_s p[b,h(w),s]*x[b,c,s,w]
// (the pos-branch weighted x-average; consumed by k_attn's inline vbar).
// ---------------------------------------------------------------------------
__global__ __launch_bounds__(256) void k_qkv(
    const float* __restrict__ x,
    const unsigned short* __restrict__ packs,
    const float* __restrict__ sv, const float* __restrict__ svq,
    const float* __restrict__ p_g,
    unsigned short* __restrict__ yq, unsigned short* __restrict__ yk,
    unsigned short* __restrict__ yvT, float* __restrict__ xbar)
{
    __shared__ float xr_s[4][8];
    const int tid  = threadIdx.x;
    const int wv   = tid >> 6;
    const int lane = tid & 63;
    const int quad = lane >> 4;
    const int l15  = lane & 15;

    if (blockIdx.x >= 512) {
        // ---- xbar blocks ----
        const int bi = blockIdx.x - 512;
        const int b = bi >> 6, c = bi & 63;
        const float* xc = x + (size_t)b * 524288 + c * 8192;
        const float* pb = p_g + b * 4096;
        float acc[8] = {};
        #pragma unroll
        for (int rr = 0; rr < 4; ++rr) {
            const int s = tid * 4 + rr;
            f32x4 x0 = *(const f32x4*)(xc + s * 8);
            f32x4 x1 = *(const f32x4*)(xc + s * 8 + 4);
            float p0 = pb[s], p1 = pb[1024 + s], p2 = pb[2048 + s], p3 = pb[3072 + s];
            acc[0] += p0 * x0[0]; acc[1] += p0 * x0[1];
            acc[2] += p1 * x0[2]; acc[3] += p1 * x0[3];
            acc[4] += p2 * x1[0]; acc[5] += p2 * x1[1];
            acc[6] += p3 * x1[2]; acc[7] += p3 * x1[3];
        }
        #pragma unroll
        for (int j = 0; j < 8; ++j)
            #pragma unroll
            for (int off = 1; off < 64; off <<= 1)
                acc[j] += __shfl_xor(acc[j], off);
        if (lane == 0)
            #pragma unroll
            for (int j = 0; j < 8; ++j) xr_s[wv][j] = acc[j];
        __syncthreads();
        if (tid < 8)
            xbar[(b * 8 + tid) * 64 + c] = xr_s[0][tid] + xr_s[1][tid]
                                         + xr_s[2][tid] + xr_s[3][tid];
        return;
    }

    // ---- projection blocks ----
    const int r0   = blockIdx.x * 64 + wv * 16;
    const int b    = r0 >> 13;
    const int rloc = (r0 & 8191) + l15;
    const float* xb = x + (size_t)b * 524288;

    // B fragments (x^T), hi/lo split
    u32x4 bhi[2], blo[2];
    #pragma unroll
    for (int kc = 0; kc < 2; ++kc) {
        float xv[8];
        #pragma unroll
        for (int j = 0; j < 8; ++j)
            xv[j] = xb[(kc * 32 + quad * 8 + j) * 8192 + rloc];
        pack_hilo(xv, bhi[kc], blo[kc]);
    }

    f32x4 svA[4], svQ[4];
    #pragma unroll
    for (int mt = 0; mt < 4; ++mt) {
        svA[mt] = *(const f32x4*)(sv + mt * 16 + quad * 4);
        svQ[mt] = *(const f32x4*)(svq + mt * 16 + quad * 4);
    }

    const int row_g  = r0 + l15;
    const int s_idx  = (row_g >> 3) & 1023;
    const int w_idx  = row_g & 7;
    const int bh_v   = b * 4 + (w_idx >> 1);
    unsigned short* vtb = yvT + ((size_t)(bh_v * HD + (w_idx & 1) * 64)) * S_ + s_idx;

    for (int mat = 0; mat < 3; ++mat) {
        const unsigned short* mh = packs + mat * 8192;
        const unsigned short* ml = mh + 4096;

        f32x4 acc[4] = {};
        #pragma unroll
        for (int kc = 0; kc < 2; ++kc)
            #pragma unroll
            for (int mt = 0; mt < 4; ++mt) {
                const int off = (mt * 16 + l15) * 64 + kc * 32 + quad * 8;
                u32x4 ahi = *(const u32x4*)(mh + off);
                u32x4 alo = *(const u32x4*)(ml + off);
                acc[mt] = __builtin_amdgcn_mfma_f32_16x16x32_bf16(
                    __builtin_bit_cast(short8, ahi),
                    __builtin_bit_cast(short8, bhi[kc]), acc[mt], 0, 0, 0);
                acc[mt] = __builtin_amdgcn_mfma_f32_16x16x32_bf16(
                    __builtin_bit_cast(short8, ahi),
                    __builtin_bit_cast(short8, blo[kc]), acc[mt], 0, 0, 0);
                acc[mt] = __builtin_amdgcn_mfma_f32_16x16x32_bf16(
                    __builtin_bit_cast(short8, alo),
                    __builtin_bit_cast(short8, bhi[kc]), acc[mt], 0, 0, 0);
            }

        if (mat < 2) {
            const f32x4* svp = (mat == 0) ? svQ : svA;
            unsigned short* y = (mat == 0 ? yq : yk);
            #pragma unroll
            for (int mt = 0; mt < 4; ++mt) {
                float v0 = acc[mt][0] + svp[mt][0];
                float v1 = acc[mt][1] + svp[mt][1];
                float v2 = acc[mt][2] + svp[mt][2];
                float v3 = acc[mt][3] + svp[mt][3];
                u32x2 pk;
                pk[0] = (unsigned int)f2bf(v0) | ((unsigned int)f2bf(v1) << 16);
                pk[1] = (unsigned int)f2bf(v2) | ((unsigned int)f2bf(v3) << 16);
                *(u32x2*)(y + (size_t)row_g * 64 + mt * 16 + quad * 4) = pk;
            }
        } else {
            #pragma unroll
            for (int mt = 0; mt < 4; ++mt)
                #pragma unroll
                for (int rr = 0; rr < 4; ++rr) {
                    const int c = mt * 16 + quad * 4 + rr;
                    vtb[(size_t)c * S_] = f2bf(acc[mt][rr] + svA[mt][rr]);
                }
        }
    }
}

// ---------------------------------------------------------------------------
// K2 k_attn: flash attention with NO-MAX softmax (p = exp(S - 4); |S|<<88 by
// construction).  No running max, no alpha rescale, ZERO cross-lane ops in
// the main loop -> iterations carry only accumulator deps and pipeline.
// Block = 4 waves = 4 S-chunks of 256 t for one (bh, 16-q-row) tile.
// vbar reconstructed in the prologue from xbar (pos branch, rank-1).
// ---------------------------------------------------------------------------
__global__ __launch_bounds__(256, 4) void k_attn(
    const unsigned short* __restrict__ yq, const unsigned short* __restrict__ yk,
    const unsigned short* __restrict__ yvT,
    const float* __restrict__ xbar, const float* __restrict__ vw,
    const int* __restrict__ embed_id, const float* __restrict__ sv,
    const float* __restrict__ gate, float* __restrict__ out)
{
    __shared__ __align__(16) float acc_s[4][16 * 132];
    __shared__ float lch_s[4][16];
    __shared__ float vbar_s[128];

    const int tid  = threadIdx.x;
    const int w    = tid >> 6;
    const int lane = tid & 63;
    const int quad = lane >> 4;
    const int l15  = lane & 15;
    const int bh = blockIdx.x & 15, qt = blockIdx.x >> 4;
    const int b = bh >> 2, h = bh & 3;
    const int s0 = qt * 16;

    // ---- prologue: vbar[dd] = ve[c,:] . xbar[b][w_idx] + sv[c] ----
    if (tid < 128) {
        const int c = tid & 63, wloc = tid >> 6;
        const float* ver = vw + embed_id[0] * 4096 + c * 64;
        const float* xbr = xbar + (b * 8 + h * 2 + wloc) * 64;
        float a = sv[c];
        #pragma unroll
        for (int j4 = 0; j4 < 16; ++j4) {
            f32x4 e4 = *(const f32x4*)(ver + j4 * 4);
            f32x4 x4 = *(const f32x4*)(xbr + j4 * 4);
            a += e4[0] * x4[0] + e4[1] * x4[1] + e4[2] * x4[2] + e4[3] * x4[3];
        }
        vbar_s[tid] = a;
    }

    // Q fragments (B-operand of S^T = K Q^T)
    u32x4 qf[4];
    #pragma unroll
    for (int kc = 0; kc < 4; ++kc)
        qf[kc] = *(const u32x4*)(yq +
            (size_t)(b * S_ + s0 + l15) * F_ + h * HD + kc * 32 + quad * 8);

    f32x4 o[8] = {};
    float lsum = 0.f;
    const int srcA = ((quad & 1) << 5) + l15;
    const unsigned short* ykb = yk + (size_t)(b * S_) * F_ + h * HD;
    const unsigned short* yvb = yvT + (size_t)(bh * HD) * S_;

    #pragma unroll 2
    for (int it = 0; it < 8; ++it) {
        const int t0 = w * 256 + it * 32;

        // S^T = K Q^T (two 16-t subtiles)
        u32x4 kf0[4], kf1[4];
        #pragma unroll
        for (int kc = 0; kc < 4; ++kc)
            kf0[kc] = *(const u32x4*)(ykb + (size_t)(t0 + l15) * F_ + kc * 32 + quad * 8);
        #pragma unroll
        for (int kc = 0; kc < 4; ++kc)
            kf1[kc] = *(const u32x4*)(ykb + (size_t)(t0 + 16 + l15) * F_ + kc * 32 + quad * 8);
        f32x4 sa0 = {}, sa1 = {};
        #pragma unroll
        for (int kc = 0; kc < 4; ++kc)
            sa0 = __builtin_amdgcn_mfma_f32_16x16x32_bf16(
                __builtin_bit_cast(short8, kf0[kc]),
                __builtin_bit_cast(short8, qf[kc]), sa0, 0, 0, 0);
        #pragma unroll
        for (int kc = 0; kc < 4; ++kc)
            sa1 = __builtin_amdgcn_mfma_f32_16x16x32_bf16(
                __builtin_bit_cast(short8, kf1[kc]),
                __builtin_bit_cast(short8, qf[kc]), sa1, 0, 0, 0);

        // p = exp(S - C); per-lane partial l (no cross-lane traffic)
        float p0[4], p1[4];
        #pragma unroll
        for (int r = 0; r < 4; ++r) {
            p0[r] = __expf(sa0[r] - SOFT_C);
            p1[r] = __expf(sa1[r] - SOFT_C);
            lsum += p0[r] + p1[r];
        }

        // P (C-layout) -> B-fragment of PV^T via quad-permute shuffles
        unsigned int pk00 = (unsigned int)f2bf(p0[0]) | ((unsigned int)f2bf(p0[1]) << 16);
        unsigned int pk01 = (unsigned int)f2bf(p0[2]) | ((unsigned int)f2bf(p0[3]) << 16);
        unsigned int pk10 = (unsigned int)f2bf(p1[0]) | ((unsigned int)f2bf(p1[1]) << 16);
        unsigned int pk11 = (unsigned int)f2bf(p1[2]) | ((unsigned int)f2bf(p1[3]) << 16);
        unsigned int sel0 = (quad < 2) ? pk00 : pk10;
        unsigned int sel1 = (quad < 2) ? pk01 : pk11;
        u32x4 pf;
        pf[0] = (unsigned int)__shfl((int)sel0, srcA);
        pf[1] = (unsigned int)__shfl((int)sel1, srcA);
        pf[2] = (unsigned int)__shfl((int)sel0, srcA + 16);
        pf[3] = (unsigned int)__shfl((int)sel1, srcA + 16);

        // O^T += V^T P^T
        #pragma unroll
        for (int dt = 0; dt < 8; ++dt) {
            u32x4 vf = *(const u32x4*)(yvb + (size_t)(dt * 16 + l15) * S_ + t0 + quad * 8);
            o[dt] = __builtin_amdgcn_mfma_f32_16x16x32_bf16(
                __builtin_bit_cast(short8, vf),
                __builtin_bit_cast(short8, pf), o[dt], 0, 0, 0);
        }
    }

    // ---- chunk epilogue: fold quads of l once; park partials in LDS ----
    lsum += __shfl_xor(lsum, 16);
    lsum += __shfl_xor(lsum, 32);
    if (quad == 0) lch_s[w][l15] = lsum;
    float* my = acc_s[w];
    #pragma unroll
    for (int dt = 0; dt < 8; ++dt)
        *(f32x4*)&my[l15 * 132 + dt * 16 + quad * 4] = o[dt];
    __syncthreads();

    // ---- combine 4 chunks (plain sums: no max bookkeeping) + gate ----
    const int row = tid >> 4, d0 = (tid & 15) * 8;
    const float L = lch_s[0][row] + lch_s[1][row] + lch_s[2][row] + lch_s[3][row];
    float y0[4] = {}, y1[4] = {};
    #pragma unroll
    for (int c = 0; c < 4; ++c) {
        f32x4 a0 = *(const f32x4*)&acc_s[c][row * 132 + d0];
        f32x4 a1 = *(const f32x4*)&acc_s[c][row * 132 + d0 + 4];
        #pragma unroll
        for (int j = 0; j < 4; ++j) { y0[j] += a0[j]; y1[j] += a1[j]; }
    }
    const float gf = 1.f / (1.f + __expf(-gate[h]));
    const float cf = (1.f - gf) / L;
    f32x4 r0v, r1v;
    #pragma unroll
    for (int j = 0; j < 4; ++j) {
        r0v[j] = cf * y0[j] + gf * vbar_s[d0 + j];
        r1v[j] = cf * y1[j] + gf * vbar_s[d0 + 4 + j];
    }
    float* op = out + (size_t)(b * S_ + s0 + row) * F_ + h * HD + d0;
    *(f32x4*)op = r0v;
    *(f32x4*)(op + 4) = r1v;
}

// ---------------------------------------------------------------------------
// K3 k_oproj: output projection as MFMA, PREPACKED out_w hi/lo, in-place.
// ---------------------------------------------------------------------------
__global__ __launch_bounds__(256) void k_oproj(
    float* __restrict__ out, const unsigned short* __restrict__ packs,
    const float* __restrict__ ob)
{
    const int tid  = threadIdx.x;
    const int wv   = tid >> 6;
    const int lane = tid & 63;
    const int quad = lane >> 4;
    const int l15  = lane & 15;
    const int r0   = blockIdx.x * 64 + wv * 16;
    const unsigned short* owh = packs + 3 * 8192;
    const unsigned short* owl = owh + 4096;

    u32x4 bhi[2], blo[2];
    #pragma unroll
    for (int kc = 0; kc < 2; ++kc) {
        const float* src = out + (size_t)(r0 + l15) * 64 + kc * 32 + quad * 8;
        f32x4 y0 = *(const f32x4*)src;
        f32x4 y1 = *(const f32x4*)(src + 4);
        float yv8[8] = {y0[0], y0[1], y0[2], y0[3], y1[0], y1[1], y1[2], y1[3]};
        pack_hilo(yv8, bhi[kc], blo[kc]);
    }

    f32x4 acc[4] = {};
    #pragma unroll
    for (int kc = 0; kc < 2; ++kc)
        #pragma unroll
        for (int mt = 0; mt < 4; ++mt) {
            const int off = (mt * 16 + l15) * 64 + kc * 32 + quad * 8;
            u32x4 ahi = *(const u32x4*)(owh + off);
            u32x4 alo = *(const u32x4*)(owl + off);
            acc[mt] = __builtin_amdgcn_mfma_f32_16x16x32_bf16(
                __builtin_bit_cast(short8, ahi),
                __builtin_bit_cast(short8, bhi[kc]), acc[mt], 0, 0, 0);
            acc[mt] = __builtin_amdgcn_mfma_f32_16x16x32_bf16(
                __builtin_bit_cast(short8, ahi),
                __builtin_bit_cast(short8, blo[kc]), acc[mt], 0, 0, 0);
            acc[mt] = __builtin_amdgcn_mfma_f32_16x16x32_bf16(
                __builtin_bit_cast(short8, alo),
                __builtin_bit_cast(short8, bhi[kc]), acc[mt], 0, 0, 0);
        }

    #pragma unroll
    for (int mt = 0; mt < 4; ++mt) {
        f32x4 bias = *(const f32x4*)(ob + mt * 16 + quad * 4);
        f32x4 v = acc[mt] + bias;
        *(f32x4*)(out + (size_t)(r0 + l15) * 64 + mt * 16 + quad * 4) = v;
    }
}

extern "C" void kernel_launch(void* const* d_in, const int* in_sizes, int n_in,
                              void* d_out, int out_size, void* d_ws, size_t ws_size,
                              hipStream_t stream) {
    (void)in_sizes; (void)n_in; (void)out_size; (void)ws_size;
    const float* x        = (const float*)d_in[0];
    const float* pos      = (const float*)d_in[1];
    const float* strength = (const float*)d_in[2];
    const int*   embed_id = (const int*)d_in[3];
    const float* qw       = (const float*)d_in[4];
    const float* kw       = (const float*)d_in[5];
    const float* vw       = (const float*)d_in[6];
    const float* pw1      = (const float*)d_in[7];
    const float* pb1      = (const float*)d_in[8];
    const float* pw2      = (const float*)d_in[9];
    const float* pb2      = (const float*)d_in[10];
    const float* head_w   = (const float*)d_in[11];
    const float* gate     = (const float*)d_in[13];
    const float* out_w    = (const float*)d_in[14];
    const float* out_b    = (const float*)d_in[15];
    const float* str_w    = (const float*)d_in[16];
    const float* str_b    = (const float*)d_in[17];
    float* out = (float*)d_out;

    unsigned short* yq    = (unsigned short*)d_ws;         // 4 MiB
    unsigned short* yk    = yq + 2097152;                  // 4 MiB
    unsigned short* yvT   = yk + 2097152;                  // 4 MiB
    unsigned short* packs = yvT + 2097152;                 // 8 x 4096 shorts
    float* sv   = (float*)(packs + 8 * 4096);              // 64
    float* svq  = sv + 64;                                 // 64
    float* p_g  = svq + 64;                                // 16384
    float* xbar = p_g + 16384;                             // 2048

    k_prep<<<9, 256, 0, stream>>>(embed_id, qw, kw, vw, out_w, pos,
                                  pw1, pb1, pw2, pb2, head_w,
                                  strength, str_w, str_b, packs, sv, svq, p_g);
    k_qkv<<<768, 256, 0, stream>>>(x, packs, sv, svq, p_g, yq, yk, yvT, xbar);
    k_attn<<<1024, 256, 0, stream>>>(yq, yk, yvT, xbar, vw, embed_id, sv,
                                     gate, out);
    k_oproj<<<512, 256, 0, stream>>>(out, packs, out_b);
}

// Round 6
// 158.173 us; speedup vs baseline: 1.2774x; 1.2187x over previous
//
#include <hip/hip_runtime.h>
#include <math.h>
#include <stdint.h>

#define B_ 4
#define S_ 1024
#define F_ 512    // W*DIM = HEADS*HD
#define HD 128
#define SOFT_C 4.0f   // fixed exp-centering; |S| << 88 so no running max needed

typedef __attribute__((ext_vector_type(8))) short short8;
typedef __attribute__((ext_vector_type(4))) float f32x4;
typedef __attribute__((ext_vector_type(4))) unsigned int u32x4;
typedef __attribute__((ext_vector_type(2))) unsigned int u32x2;

__device__ __forceinline__ unsigned short f2bf(float f) {
    unsigned int u = __float_as_uint(f);
    u = (u + 0x7FFFu + ((u >> 16) & 1u)) >> 16;
    return (unsigned short)u;
}
__device__ __forceinline__ float bf2f(unsigned int s) {
    return __uint_as_float(s << 16);
}
__device__ __forceinline__ void pack_hilo(const float* v, u32x4& hi, u32x4& lo) {
    #pragma unroll
    for (int p = 0; p < 4; ++p) {
        unsigned int h0 = f2bf(v[2 * p]), h1 = f2bf(v[2 * p + 1]);
        float l0 = v[2 * p] - bf2f(h0), l1 = v[2 * p + 1] - bf2f(h1);
        hi[p] = h0 | (h1 << 16);
        lo[p] = (unsigned int)f2bf(l0) | ((unsigned int)f2bf(l1) << 16);
    }
}

// ---------------------------------------------------------------------------
// K0 k_prep: blk 0-3: pack {qw*scale, kw, vw, ow} -> bf16 hi/lo arrays.
//            blk 4-7: normalized pos-softmax p[b][h][t] (no-max exp).
//            blk 8  : strength vector sv / svq(=sv*scale).
// ---------------------------------------------------------------------------
__global__ __launch_bounds__(256) void k_prep(
    const int* __restrict__ embed_id,
    const float* __restrict__ qw, const float* __restrict__ kw,
    const float* __restrict__ vw, const float* __restrict__ ow,
    const float* __restrict__ pos,
    const float* __restrict__ pw1, const float* __restrict__ pb1,
    const float* __restrict__ pw2, const float* __restrict__ pb2,
    const float* __restrict__ head_w,
    const float* __restrict__ strength, const float* __restrict__ str_w,
    const float* __restrict__ str_b,
    unsigned short* __restrict__ packs,
    float* __restrict__ sv, float* __restrict__ svq,
    float* __restrict__ p_g)
{
    __shared__ float red_s[4][4];
    __shared__ float inv_s[4];
    const int blk = blockIdx.x, tid = threadIdx.x;
    const float SCALE = 0.08838834764831845f;

    if (blk < 4) {
        const int id = embed_id[0];
        const float* src = (blk == 0 ? qw + id * 4096 : blk == 1 ? kw + id * 4096
                            : blk == 2 ? vw + id * 4096 : ow);
        const float scale = (blk == 0) ? SCALE : 1.0f;
        unsigned short* hi = packs + blk * 8192;
        unsigned short* lo = hi + 4096;
        for (int i = tid; i < 4096; i += 256) {
            float v = src[i] * scale;
            unsigned short h = f2bf(v);
            hi[i] = h;
            lo[i] = f2bf(v - bf2f(h));
        }
    } else if (blk < 8) {
        const int b = blk - 4;
        const int wv = tid >> 6;
        float w1_[9], b1_[3], w2_[24], b2_[8], hw_[32];
        #pragma unroll
        for (int i = 0; i < 9; ++i)  w1_[i] = pw1[i];
        #pragma unroll
        for (int i = 0; i < 3; ++i)  b1_[i] = pb1[i];
        #pragma unroll
        for (int i = 0; i < 24; ++i) w2_[i] = pw2[i];
        #pragma unroll
        for (int i = 0; i < 8; ++i)  b2_[i] = pb2[i];
        #pragma unroll
        for (int i = 0; i < 32; ++i) hw_[i] = head_w[i];

        float ev[4][4];
        float ps[4] = {0.f, 0.f, 0.f, 0.f};
        #pragma unroll
        for (int k = 0; k < 4; ++k) {
            const int t = k * 256 + tid;
            float p0 = pos[(b * S_ + t) * 3 + 0];
            float p1 = pos[(b * S_ + t) * 3 + 1];
            float p2 = pos[(b * S_ + t) * 3 + 2];
            float h0 = fmaxf(0.f, p0 * w1_[0] + p1 * w1_[1] + p2 * w1_[2] + b1_[0]);
            float h1 = fmaxf(0.f, p0 * w1_[3] + p1 * w1_[4] + p2 * w1_[5] + b1_[1]);
            float h2 = fmaxf(0.f, p0 * w1_[6] + p1 * w1_[7] + p2 * w1_[8] + b1_[2]);
            float ph[8];
            #pragma unroll
            for (int o8 = 0; o8 < 8; ++o8)
                ph[o8] = h0 * w2_[o8 * 3] + h1 * w2_[o8 * 3 + 1] + h2 * w2_[o8 * 3 + 2] + b2_[o8];
            #pragma unroll
            for (int h = 0; h < 4; ++h) {
                float A = 0.f;
                #pragma unroll
                for (int o8 = 0; o8 < 8; ++o8) A += ph[o8] * hw_[h * 8 + o8];
                ev[k][h] = __expf(-A - 1.0f);
                ps[h] += ev[k][h];
            }
        }
        #pragma unroll
        for (int h = 0; h < 4; ++h)
            #pragma unroll
            for (int off = 1; off < 64; off <<= 1)
                ps[h] += __shfl_xor(ps[h], off);
        if ((tid & 63) == 0)
            #pragma unroll
            for (int h = 0; h < 4; ++h) red_s[wv][h] = ps[h];
        __syncthreads();
        if (tid < 4)
            inv_s[tid] = 1.f / (red_s[0][tid] + red_s[1][tid] + red_s[2][tid] + red_s[3][tid]);
        __syncthreads();
        #pragma unroll
        for (int k = 0; k < 4; ++k)
            #pragma unroll
            for (int h = 0; h < 4; ++h)
                p_g[(b * 4 + h) * S_ + k * 256 + tid] = ev[k][h] * inv_s[h];
    } else {
        __shared__ float part_s[4][64];
        const int c = tid & 63, pr = tid >> 6;
        const float* wrow = str_w + c * 512 + pr * 128;
        const float* st   = strength + pr * 128;
        float acc = 0.f;
        #pragma unroll
        for (int j4 = 0; j4 < 32; ++j4) {
            f32x4 wv4 = *(const f32x4*)(wrow + j4 * 4);
            f32x4 s4  = *(const f32x4*)(st + j4 * 4);
            acc += wv4[0] * s4[0] + wv4[1] * s4[1] + wv4[2] * s4[2] + wv4[3] * s4[3];
        }
        part_s[pr][c] = acc;
        __syncthreads();
        if (tid < 64) {
            float v = part_s[0][tid] + part_s[1][tid] + part_s[2][tid]
                    + part_s[3][tid] + str_b[tid];
            sv[tid] = v;
            svq[tid] = v * SCALE;
        }
    }
}

// ---------------------------------------------------------------------------
// K1 k_qkv: QKV MFMA GEMM (prepacked emb).  NEW per-head output layouts so
// k_attn can stage contiguous tiles:
//   yqh/ykh[bh][s][d=128]   (256B rows, contiguous per head)
//   yvt2[bh][s/64][d][s%64] (tile-blocked: each 64-t x 128-d V tile = 16KB
//                            contiguous)
// blk>=512: xbar[b][w][c] = sum_s p[b,h(w),s]*x[b,c,s,w]  (pos branch).
// ---------------------------------------------------------------------------
__global__ __launch_bounds__(256) void k_qkv(
    const float* __restrict__ x,
    const unsigned short* __restrict__ packs,
    const float* __restrict__ sv, const float* __restrict__ svq,
    const float* __restrict__ p_g,
    unsigned short* __restrict__ yqh, unsigned short* __restrict__ ykh,
    unsigned short* __restrict__ yvt2, float* __restrict__ xbar)
{
    __shared__ float xr_s[4][8];
    const int tid  = threadIdx.x;
    const int wv   = tid >> 6;
    const int lane = tid & 63;
    const int quad = lane >> 4;
    const int l15  = lane & 15;

    if (blockIdx.x >= 512) {
        const int bi = blockIdx.x - 512;
        const int b = bi >> 6, c = bi & 63;
        const float* xc = x + (size_t)b * 524288 + c * 8192;
        const float* pb = p_g + b * 4096;
        float acc[8] = {};
        #pragma unroll
        for (int rr = 0; rr < 4; ++rr) {
            const int s = tid * 4 + rr;
            f32x4 x0 = *(const f32x4*)(xc + s * 8);
            f32x4 x1 = *(const f32x4*)(xc + s * 8 + 4);
            float p0 = pb[s], p1 = pb[1024 + s], p2 = pb[2048 + s], p3 = pb[3072 + s];
            acc[0] += p0 * x0[0]; acc[1] += p0 * x0[1];
            acc[2] += p1 * x0[2]; acc[3] += p1 * x0[3];
            acc[4] += p2 * x1[0]; acc[5] += p2 * x1[1];
            acc[6] += p3 * x1[2]; acc[7] += p3 * x1[3];
        }
        #pragma unroll
        for (int j = 0; j < 8; ++j)
            #pragma unroll
            for (int off = 1; off < 64; off <<= 1)
                acc[j] += __shfl_xor(acc[j], off);
        if (lane == 0)
            #pragma unroll
            for (int j = 0; j < 8; ++j) xr_s[wv][j] = acc[j];
        __syncthreads();
        if (tid < 8)
            xbar[(b * 8 + tid) * 64 + c] = xr_s[0][tid] + xr_s[1][tid]
                                         + xr_s[2][tid] + xr_s[3][tid];
        return;
    }

    const int r0   = blockIdx.x * 64 + wv * 16;
    const int b    = r0 >> 13;
    const int rloc = (r0 & 8191) + l15;
    const float* xb = x + (size_t)b * 524288;

    // B fragments (x^T), hi/lo split
    u32x4 bhi[2], blo[2];
    #pragma unroll
    for (int kc = 0; kc < 2; ++kc) {
        float xv[8];
        #pragma unroll
        for (int j = 0; j < 8; ++j)
            xv[j] = xb[(kc * 32 + quad * 8 + j) * 8192 + rloc];
        pack_hilo(xv, bhi[kc], blo[kc]);
    }

    f32x4 svA[4], svQ[4];
    #pragma unroll
    for (int mt = 0; mt < 4; ++mt) {
        svA[mt] = *(const f32x4*)(sv + mt * 16 + quad * 4);
        svQ[mt] = *(const f32x4*)(svq + mt * 16 + quad * 4);
    }

    // store geometry
    const int row_g = r0 + l15;
    const int s_idx = (row_g >> 3) & 1023;
    const int w_idx = row_g & 7;
    const int bh    = b * 4 + (w_idx >> 1);
    const int dbase = (w_idx & 1) * 64;
    unsigned short* qkbase_q = yqh + (size_t)bh * 131072 + s_idx * 128 + dbase;
    unsigned short* qkbase_k = ykh + (size_t)bh * 131072 + s_idx * 128 + dbase;
    unsigned short* vtb = yvt2 + (size_t)bh * 131072 + (s_idx >> 6) * 8192
                        + (size_t)dbase * 64 + (s_idx & 63);

    for (int mat = 0; mat < 3; ++mat) {
        const unsigned short* mh = packs + mat * 8192;
        const unsigned short* ml = mh + 4096;

        f32x4 acc[4] = {};
        #pragma unroll
        for (int kc = 0; kc < 2; ++kc)
            #pragma unroll
            for (int mt = 0; mt < 4; ++mt) {
                const int off = (mt * 16 + l15) * 64 + kc * 32 + quad * 8;
                u32x4 ahi = *(const u32x4*)(mh + off);
                u32x4 alo = *(const u32x4*)(ml + off);
                acc[mt] = __builtin_amdgcn_mfma_f32_16x16x32_bf16(
                    __builtin_bit_cast(short8, ahi),
                    __builtin_bit_cast(short8, bhi[kc]), acc[mt], 0, 0, 0);
                acc[mt] = __builtin_amdgcn_mfma_f32_16x16x32_bf16(
                    __builtin_bit_cast(short8, ahi),
                    __builtin_bit_cast(short8, blo[kc]), acc[mt], 0, 0, 0);
                acc[mt] = __builtin_amdgcn_mfma_f32_16x16x32_bf16(
                    __builtin_bit_cast(short8, alo),
                    __builtin_bit_cast(short8, bhi[kc]), acc[mt], 0, 0, 0);
            }

        if (mat < 2) {
            const f32x4* svp = (mat == 0) ? svQ : svA;
            unsigned short* y = (mat == 0 ? qkbase_q : qkbase_k);
            #pragma unroll
            for (int mt = 0; mt < 4; ++mt) {
                float v0 = acc[mt][0] + svp[mt][0];
                float v1 = acc[mt][1] + svp[mt][1];
                float v2 = acc[mt][2] + svp[mt][2];
                float v3 = acc[mt][3] + svp[mt][3];
                u32x2 pk;
                pk[0] = (unsigned int)f2bf(v0) | ((unsigned int)f2bf(v1) << 16);
                pk[1] = (unsigned int)f2bf(v2) | ((unsigned int)f2bf(v3) << 16);
                *(u32x2*)(y + mt * 16 + quad * 4) = pk;
            }
        } else {
            #pragma unroll
            for (int mt = 0; mt < 4; ++mt)
                #pragma unroll
                for (int rr = 0; rr < 4; ++rr) {
                    const int c = mt * 16 + quad * 4 + rr;
                    vtb[(size_t)c * 64] = f2bf(acc[mt][rr] + svA[mt][rr]);
                }
        }
    }
}

// ---------------------------------------------------------------------------
// K2 k_attn: canonical LDS-staged flash attention.
// Grid 512 = 16 bh x 32 q-tiles (32 rows).  Block 4 waves; wave w owns the
// (q-half = w>>1, d-half = w&1) quadrant (16 q x 64 d).  QK^T duplicated
// across d-halves to stay wave-local.
// K/V 64-t tiles staged contiguously (16KB each) into padded LDS, double-
// buffered, 1 barrier/tile; fragments via ds_read_b128.  No-max softmax
// (p = exp(S-4)), quad-shuffle P transpose, per-lane l (lane = q-row).
// ---------------------------------------------------------------------------
__global__ __launch_bounds__(256, 2) void k_attn(
    const unsigned short* __restrict__ yqh, const unsigned short* __restrict__ ykh,
    const unsigned short* __restrict__ yvt2,
    const float* __restrict__ xbar, const float* __restrict__ vw,
    const int* __restrict__ embed_id, const float* __restrict__ sv,
    const float* __restrict__ gate, float* __restrict__ out)
{
    __shared__ __align__(16) unsigned short kx[2][64 * 136];   // [t][128+8]
    __shared__ __align__(16) unsigned short vx[2][128 * 72];   // [d][64+8]
    __shared__ float vbar_s[128];

    const int tid  = threadIdx.x;
    const int w    = tid >> 6;
    const int lane = tid & 63;
    const int quad = lane >> 4;
    const int l15  = lane & 15;
    const int bh = blockIdx.x & 15, qt = blockIdx.x >> 4;
    const int b = bh >> 2, h = bh & 3;
    const int s0 = qt * 32;
    const int qh = w >> 1;        // q-half (16 rows)
    const int dh = w & 1;         // d-half (64 cols)

    const unsigned short* ykb = ykh + (size_t)bh * 131072;
    const unsigned short* yvb = yvt2 + (size_t)bh * 131072;

    // ---- vbar prologue (pos branch, rank-1 reconstruction) ----
    if (tid < 128) {
        const int c = tid & 63, wloc = tid >> 6;
        const float* ver = vw + embed_id[0] * 4096 + c * 64;
        const float* xbr = xbar + (b * 8 + h * 2 + wloc) * 64;
        float a = sv[c];
        #pragma unroll
        for (int j4 = 0; j4 < 16; ++j4) {
            f32x4 e4 = *(const f32x4*)(ver + j4 * 4);
            f32x4 x4 = *(const f32x4*)(xbr + j4 * 4);
            a += e4[0] * x4[0] + e4[1] * x4[1] + e4[2] * x4[2] + e4[3] * x4[3];
        }
        vbar_s[wloc * 64 + c] = a;
    }

    // ---- Q fragments: B[n=q(l15)][k=d(quad*8+j)], kc = 0..3 ----
    u32x4 qf[4];
    #pragma unroll
    for (int kc = 0; kc < 4; ++kc)
        qf[kc] = *(const u32x4*)(yqh + (size_t)bh * 131072
                 + (s0 + qh * 16 + l15) * 128 + kc * 32 + quad * 8);

    // ---- stage tile 0 ----
    #pragma unroll
    for (int r = 0; r < 4; ++r) {
        const int off = r * 2048 + tid * 8;
        *(u32x4*)&kx[0][(off >> 7) * 136 + (off & 127)] =
            *(const u32x4*)(ykb + off);
        *(u32x4*)&vx[0][(off >> 6) * 72 + (off & 63)] =
            *(const u32x4*)(yvb + off);
    }
    __syncthreads();

    f32x4 o[4] = {};
    float lsum = 0.f;
    const int srcA = ((quad & 1) << 5) + l15;

    for (int it = 0; it < 16; ++it) {
        const int cur = it & 1;
        u32x4 kst[4], vst[4];
        const bool pre = (it < 15);
        if (pre) {
            const unsigned short* ksrc = ykb + (it + 1) * 8192;
            const unsigned short* vsrc = yvb + (it + 1) * 8192;
            #pragma unroll
            for (int r = 0; r < 4; ++r)
                kst[r] = *(const u32x4*)(ksrc + r * 2048 + tid * 8);
            #pragma unroll
            for (int r = 0; r < 4; ++r)
                vst[r] = *(const u32x4*)(vsrc + r * 2048 + tid * 8);
        }

        const unsigned short* kxc = kx[cur];
        const unsigned short* vxc = vx[cur];

        #pragma unroll
        for (int th = 0; th < 2; ++th) {
            // S^T = K Q^T over two 16-t subtiles
            f32x4 sa0 = {}, sa1 = {};
            #pragma unroll
            for (int kc = 0; kc < 4; ++kc) {
                u32x4 a0 = *(const u32x4*)&kxc[(th * 32 + l15) * 136 + kc * 32 + quad * 8];
                sa0 = __builtin_amdgcn_mfma_f32_16x16x32_bf16(
                    __builtin_bit_cast(short8, a0),
                    __builtin_bit_cast(short8, qf[kc]), sa0, 0, 0, 0);
            }
            #pragma unroll
            for (int kc = 0; kc < 4; ++kc) {
                u32x4 a1 = *(const u32x4*)&kxc[(th * 32 + 16 + l15) * 136 + kc * 32 + quad * 8];
                sa1 = __builtin_amdgcn_mfma_f32_16x16x32_bf16(
                    __builtin_bit_cast(short8, a1),
                    __builtin_bit_cast(short8, qf[kc]), sa1, 0, 0, 0);
            }

            // p = exp(S - C); per-lane l partial (lane l15 = q-row)
            float p0[4], p1[4];
            #pragma unroll
            for (int r = 0; r < 4; ++r) {
                p0[r] = __expf(sa0[r] - SOFT_C);
                p1[r] = __expf(sa1[r] - SOFT_C);
                lsum += p0[r] + p1[r];
            }

            // P (C-layout) -> B-frag of PV^T via quad-permute shuffles
            unsigned int pk00 = (unsigned int)f2bf(p0[0]) | ((unsigned int)f2bf(p0[1]) << 16);
            unsigned int pk01 = (unsigned int)f2bf(p0[2]) | ((unsigned int)f2bf(p0[3]) << 16);
            unsigned int pk10 = (unsigned int)f2bf(p1[0]) | ((unsigned int)f2bf(p1[1]) << 16);
            unsigned int pk11 = (unsigned int)f2bf(p1[2]) | ((unsigned int)f2bf(p1[3]) << 16);
            unsigned int sel0 = (quad < 2) ? pk00 : pk10;
            unsigned int sel1 = (quad < 2) ? pk01 : pk11;
            u32x4 pf;
            pf[0] = (unsigned int)__shfl((int)sel0, srcA);
            pf[1] = (unsigned int)__shfl((int)sel1, srcA);
            pf[2] = (unsigned int)__shfl((int)sel0, srcA + 16);
            pf[3] = (unsigned int)__shfl((int)sel1, srcA + 16);

            // O^T += V^T P^T  (A = V from LDS, m = d)
            #pragma unroll
            for (int dt = 0; dt < 4; ++dt) {
                u32x4 vf = *(const u32x4*)&vxc[(dh * 64 + dt * 16 + l15) * 72
                                               + th * 32 + quad * 8];
                o[dt] = __builtin_amdgcn_mfma_f32_16x16x32_bf16(
                    __builtin_bit_cast(short8, vf),
                    __builtin_bit_cast(short8, pf), o[dt], 0, 0, 0);
            }
        }

        if (pre) {
            #pragma unroll
            for (int r = 0; r < 4; ++r) {
                const int off = r * 2048 + tid * 8;
                *(u32x4*)&kx[cur ^ 1][(off >> 7) * 136 + (off & 127)] = kst[r];
            }
            #pragma unroll
            for (int r = 0; r < 4; ++r) {
                const int off = r * 2048 + tid * 8;
                *(u32x4*)&vx[cur ^ 1][(off >> 6) * 72 + (off & 63)] = vst[r];
            }
        }
        __syncthreads();
    }

    // ---- epilogue: fold l across quads (lane = q), normalize, gate ----
    lsum += __shfl_xor(lsum, 16);
    lsum += __shfl_xor(lsum, 32);
    const float gf = 1.f / (1.f + __expf(-gate[h]));
    const float cf = (1.f - gf) / lsum;
    const int row = b * S_ + s0 + qh * 16 + l15;
    #pragma unroll
    for (int dt = 0; dt < 4; ++dt) {
        const int d0 = dh * 64 + dt * 16 + quad * 4;
        f32x4 vb = *(const f32x4*)&vbar_s[d0];
        f32x4 rv;
        #pragma unroll
        for (int j = 0; j < 4; ++j) rv[j] = cf * o[dt][j] + gf * vb[j];
        *(f32x4*)(out + (size_t)row * F_ + h * HD + d0) = rv;
    }
}

// ---------------------------------------------------------------------------
// K3 k_oproj: output projection as MFMA, prepacked out_w hi/lo, in-place.
// ---------------------------------------------------------------------------
__global__ __launch_bounds__(256) void k_oproj(
    float* __restrict__ out, const unsigned short* __restrict__ packs,
    const float* __restrict__ ob)
{
    const int tid  = threadIdx.x;
    const int wv   = tid >> 6;
    const int lane = tid & 63;
    const int quad = lane >> 4;
    const int l15  = lane & 15;
    const int r0   = blockIdx.x * 64 + wv * 16;
    const unsigned short* owh = packs + 3 * 8192;
    const unsigned short* owl = owh + 4096;

    u32x4 bhi[2], blo[2];
    #pragma unroll
    for (int kc = 0; kc < 2; ++kc) {
        const float* src = out + (size_t)(r0 + l15) * 64 + kc * 32 + quad * 8;
        f32x4 y0 = *(const f32x4*)src;
        f32x4 y1 = *(const f32x4*)(src + 4);
        float yv8[8] = {y0[0], y0[1], y0[2], y0[3], y1[0], y1[1], y1[2], y1[3]};
        pack_hilo(yv8, bhi[kc], blo[kc]);
    }

    f32x4 acc[4] = {};
    #pragma unroll
    for (int kc = 0; kc < 2; ++kc)
        #pragma unroll
        for (int mt = 0; mt < 4; ++mt) {
            const int off = (mt * 16 + l15) * 64 + kc * 32 + quad * 8;
            u32x4 ahi = *(const u32x4*)(owh + off);
            u32x4 alo = *(const u32x4*)(owl + off);
            acc[mt] = __builtin_amdgcn_mfma_f32_16x16x32_bf16(
                __builtin_bit_cast(short8, ahi),
                __builtin_bit_cast(short8, bhi[kc]), acc[mt], 0, 0, 0);
            acc[mt] = __builtin_amdgcn_mfma_f32_16x16x32_bf16(
                __builtin_bit_cast(short8, ahi),
                __builtin_bit_cast(short8, blo[kc]), acc[mt], 0, 0, 0);
            acc[mt] = __builtin_amdgcn_mfma_f32_16x16x32_bf16(
                __builtin_bit_cast(short8, alo),
                __builtin_bit_cast(short8, bhi[kc]), acc[mt], 0, 0, 0);
        }

    #pragma unroll
    for (int mt = 0; mt < 4; ++mt) {
        f32x4 bias = *(const f32x4*)(ob + mt * 16 + quad * 4);
        f32x4 v = acc[mt] + bias;
        *(f32x4*)(out + (size_t)(r0 + l15) * 64 + mt * 16 + quad * 4) = v;
    }
}

extern "C" void kernel_launch(void* const* d_in, const int* in_sizes, int n_in,
                              void* d_out, int out_size, void* d_ws, size_t ws_size,
                              hipStream_t stream) {
    (void)in_sizes; (void)n_in; (void)out_size; (void)ws_size;
    const float* x        = (const float*)d_in[0];
    const float* pos      = (const float*)d_in[1];
    const float* strength = (const float*)d_in[2];
    const int*   embed_id = (const int*)d_in[3];
    const float* qw       = (const float*)d_in[4];
    const float* kw       = (const float*)d_in[5];
    const float* vw       = (const float*)d_in[6];
    const float* pw1      = (const float*)d_in[7];
    const float* pb1      = (const float*)d_in[8];
    const float* pw2      = (const float*)d_in[9];
    const float* pb2      = (const float*)d_in[10];
    const float* head_w   = (const float*)d_in[11];
    const float* gate     = (const float*)d_in[13];
    const float* out_w    = (const float*)d_in[14];
    const float* out_b    = (const float*)d_in[15];
    const float* str_w    = (const float*)d_in[16];
    const float* str_b    = (const float*)d_in[17];
    float* out = (float*)d_out;

    unsigned short* yqh   = (unsigned short*)d_ws;         // 4 MiB
    unsigned short* ykh   = yqh + 2097152;                 // 4 MiB
    unsigned short* yvt2  = ykh + 2097152;                 // 4 MiB
    unsigned short* packs = yvt2 + 2097152;                // 8 x 4096 shorts
    float* sv   = (float*)(packs + 8 * 4096);              // 64
    float* svq  = sv + 64;                                 // 64
    float* p_g  = svq + 64;                                // 16384
    float* xbar = p_g + 16384;                             // 2048

    k_prep<<<9, 256, 0, stream>>>(embed_id, qw, kw, vw, out_w, pos,
                                  pw1, pb1, pw2, pb2, head_w,
                                  strength, str_w, str_b, packs, sv, svq, p_g);
    k_qkv<<<768, 256, 0, stream>>>(x, packs, sv, svq, p_g, yqh, ykh, yvt2, xbar);
    k_attn<<<512, 256, 0, stream>>>(yqh, ykh, yvt2, xbar, vw, embed_id, sv,
                                    gate, out);
    k_oproj<<<512, 256, 0, stream>>>(out, packs, out_b);
}

// Round 7
// 157.051 us; speedup vs baseline: 1.2866x; 1.0071x over previous
//
#include <hip/hip_runtime.h>
#include <math.h>
#include <stdint.h>

#define B_ 4
#define S_ 1024
#define F_ 512    // W*DIM = HEADS*HD
#define HD 128
#define SOFT_C 4.0f   // fixed exp-centering; |S| << 88 so no running max needed

typedef __attribute__((ext_vector_type(8))) short short8;
typedef __attribute__((ext_vector_type(4))) float f32x4;
typedef __attribute__((ext_vector_type(4))) unsigned int u32x4;
typedef __attribute__((ext_vector_type(2))) unsigned int u32x2;

__device__ __forceinline__ unsigned short f2bf(float f) {
    unsigned int u = __float_as_uint(f);
    u = (u + 0x7FFFu + ((u >> 16) & 1u)) >> 16;
    return (unsigned short)u;
}
__device__ __forceinline__ float bf2f(unsigned int s) {
    return __uint_as_float(s << 16);
}
__device__ __forceinline__ void pack_hilo(const float* v, u32x4& hi, u32x4& lo) {
    #pragma unroll
    for (int p = 0; p < 4; ++p) {
        unsigned int h0 = f2bf(v[2 * p]), h1 = f2bf(v[2 * p + 1]);
        float l0 = v[2 * p] - bf2f(h0), l1 = v[2 * p + 1] - bf2f(h1);
        hi[p] = h0 | (h1 << 16);
        lo[p] = (unsigned int)f2bf(l0) | ((unsigned int)f2bf(l1) << 16);
    }
}

// ---------------------------------------------------------------------------
// K0 k_prep: blk 0-3: pack {qw*scale, kw, vw, ow} -> bf16 hi/lo arrays.
//            blk 4-7: normalized pos-softmax p[b][h][t] (no-max exp).
//            blk 8  : strength vector sv / svq(=sv*scale).
// ---------------------------------------------------------------------------
__global__ __launch_bounds__(256) void k_prep(
    const int* __restrict__ embed_id,
    const float* __restrict__ qw, const float* __restrict__ kw,
    const float* __restrict__ vw, const float* __restrict__ ow,
    const float* __restrict__ pos,
    const float* __restrict__ pw1, const float* __restrict__ pb1,
    const float* __restrict__ pw2, const float* __restrict__ pb2,
    const float* __restrict__ head_w,
    const float* __restrict__ strength, const float* __restrict__ str_w,
    const float* __restrict__ str_b,
    unsigned short* __restrict__ packs,
    float* __restrict__ sv, float* __restrict__ svq,
    float* __restrict__ p_g)
{
    __shared__ float red_s[4][4];
    __shared__ float inv_s[4];
    const int blk = blockIdx.x, tid = threadIdx.x;
    const float SCALE = 0.08838834764831845f;

    if (blk < 4) {
        const int id = embed_id[0];
        const float* src = (blk == 0 ? qw + id * 4096 : blk == 1 ? kw + id * 4096
                            : blk == 2 ? vw + id * 4096 : ow);
        const float scale = (blk == 0) ? SCALE : 1.0f;
        unsigned short* hi = packs + blk * 8192;
        unsigned short* lo = hi + 4096;
        for (int i = tid; i < 4096; i += 256) {
            float v = src[i] * scale;
            unsigned short h = f2bf(v);
            hi[i] = h;
            lo[i] = f2bf(v - bf2f(h));
        }
    } else if (blk < 8) {
        const int b = blk - 4;
        const int wv = tid >> 6;
        float w1_[9], b1_[3], w2_[24], b2_[8], hw_[32];
        #pragma unroll
        for (int i = 0; i < 9; ++i)  w1_[i] = pw1[i];
        #pragma unroll
        for (int i = 0; i < 3; ++i)  b1_[i] = pb1[i];
        #pragma unroll
        for (int i = 0; i < 24; ++i) w2_[i] = pw2[i];
        #pragma unroll
        for (int i = 0; i < 8; ++i)  b2_[i] = pb2[i];
        #pragma unroll
        for (int i = 0; i < 32; ++i) hw_[i] = head_w[i];

        float ev[4][4];
        float ps[4] = {0.f, 0.f, 0.f, 0.f};
        #pragma unroll
        for (int k = 0; k < 4; ++k) {
            const int t = k * 256 + tid;
            float p0 = pos[(b * S_ + t) * 3 + 0];
            float p1 = pos[(b * S_ + t) * 3 + 1];
            float p2 = pos[(b * S_ + t) * 3 + 2];
            float h0 = fmaxf(0.f, p0 * w1_[0] + p1 * w1_[1] + p2 * w1_[2] + b1_[0]);
            float h1 = fmaxf(0.f, p0 * w1_[3] + p1 * w1_[4] + p2 * w1_[5] + b1_[1]);
            float h2 = fmaxf(0.f, p0 * w1_[6] + p1 * w1_[7] + p2 * w1_[8] + b1_[2]);
            float ph[8];
            #pragma unroll
            for (int o8 = 0; o8 < 8; ++o8)
                ph[o8] = h0 * w2_[o8 * 3] + h1 * w2_[o8 * 3 + 1] + h2 * w2_[o8 * 3 + 2] + b2_[o8];
            #pragma unroll
            for (int h = 0; h < 4; ++h) {
                float A = 0.f;
                #pragma unroll
                for (int o8 = 0; o8 < 8; ++o8) A += ph[o8] * hw_[h * 8 + o8];
                ev[k][h] = __expf(-A - 1.0f);
                ps[h] += ev[k][h];
            }
        }
        #pragma unroll
        for (int h = 0; h < 4; ++h)
            #pragma unroll
            for (int off = 1; off < 64; off <<= 1)
                ps[h] += __shfl_xor(ps[h], off);
        if ((tid & 63) == 0)
            #pragma unroll
            for (int h = 0; h < 4; ++h) red_s[wv][h] = ps[h];
        __syncthreads();
        if (tid < 4)
            inv_s[tid] = 1.f / (red_s[0][tid] + red_s[1][tid] + red_s[2][tid] + red_s[3][tid]);
        __syncthreads();
        #pragma unroll
        for (int k = 0; k < 4; ++k)
            #pragma unroll
            for (int h = 0; h < 4; ++h)
                p_g[(b * 4 + h) * S_ + k * 256 + tid] = ev[k][h] * inv_s[h];
    } else {
        __shared__ float part_s[4][64];
        const int c = tid & 63, pr = tid >> 6;
        const float* wrow = str_w + c * 512 + pr * 128;
        const float* st   = strength + pr * 128;
        float acc = 0.f;
        #pragma unroll
        for (int j4 = 0; j4 < 32; ++j4) {
            f32x4 wv4 = *(const f32x4*)(wrow + j4 * 4);
            f32x4 s4  = *(const f32x4*)(st + j4 * 4);
            acc += wv4[0] * s4[0] + wv4[1] * s4[1] + wv4[2] * s4[2] + wv4[3] * s4[3];
        }
        part_s[pr][c] = acc;
        __syncthreads();
        if (tid < 64) {
            float v = part_s[0][tid] + part_s[1][tid] + part_s[2][tid]
                    + part_s[3][tid] + str_b[tid];
            sv[tid] = v;
            svq[tid] = v * SCALE;
        }
    }
}

// ---------------------------------------------------------------------------
// K1 k_qkv: QKV MFMA GEMM (prepacked emb).
// Q/K use SWAPPED operand order mfma(A=x, B=emb): D lanes = channels ->
// stores are 32B-contiguous per 16 lanes (4x32B segments/instr) instead of
// 64x8B scatter.  V keeps mfma(A=emb, B=x): lane = row groups 8 consecutive
// s per w -> 16B segments into the tile-blocked yvt2 layout.
//   yqh/ykh[bh][s][d=128] ; yvt2[bh][s/64][d][s%64]
// blk>=512: xbar[b][w][c] = sum_s p[b,h(w),s]*x[b,c,s,w]  (pos branch).
// ---------------------------------------------------------------------------
__global__ __launch_bounds__(256) void k_qkv(
    const float* __restrict__ x,
    const unsigned short* __restrict__ packs,
    const float* __restrict__ sv, const float* __restrict__ svq,
    const float* __restrict__ p_g,
    unsigned short* __restrict__ yqh, unsigned short* __restrict__ ykh,
    unsigned short* __restrict__ yvt2, float* __restrict__ xbar)
{
    __shared__ float xr_s[4][8];
    const int tid  = threadIdx.x;
    const int wv   = tid >> 6;
    const int lane = tid & 63;
    const int quad = lane >> 4;
    const int l15  = lane & 15;

    if (blockIdx.x >= 512) {
        const int bi = blockIdx.x - 512;
        const int b = bi >> 6, c = bi & 63;
        const float* xc = x + (size_t)b * 524288 + c * 8192;
        const float* pb = p_g + b * 4096;
        float acc[8] = {};
        #pragma unroll
        for (int rr = 0; rr < 4; ++rr) {
            const int s = tid * 4 + rr;
            f32x4 x0 = *(const f32x4*)(xc + s * 8);
            f32x4 x1 = *(const f32x4*)(xc + s * 8 + 4);
            float p0 = pb[s], p1 = pb[1024 + s], p2 = pb[2048 + s], p3 = pb[3072 + s];
            acc[0] += p0 * x0[0]; acc[1] += p0 * x0[1];
            acc[2] += p1 * x0[2]; acc[3] += p1 * x0[3];
            acc[4] += p2 * x1[0]; acc[5] += p2 * x1[1];
            acc[6] += p3 * x1[2]; acc[7] += p3 * x1[3];
        }
        #pragma unroll
        for (int j = 0; j < 8; ++j)
            #pragma unroll
            for (int off = 1; off < 64; off <<= 1)
                acc[j] += __shfl_xor(acc[j], off);
        if (lane == 0)
            #pragma unroll
            for (int j = 0; j < 8; ++j) xr_s[wv][j] = acc[j];
        __syncthreads();
        if (tid < 8)
            xbar[(b * 8 + tid) * 64 + c] = xr_s[0][tid] + xr_s[1][tid]
                                         + xr_s[2][tid] + xr_s[3][tid];
        return;
    }

    const int r0   = blockIdx.x * 64 + wv * 16;
    const int b    = r0 >> 13;
    const int rloc = (r0 & 8191) + l15;
    const float* xb = x + (size_t)b * 524288;

    // x fragments (rows on l15 when used as A or B), hi/lo split
    u32x4 xhi[2], xlo[2];
    #pragma unroll
    for (int kc = 0; kc < 2; ++kc) {
        float xv[8];
        #pragma unroll
        for (int j = 0; j < 8; ++j)
            xv[j] = xb[(kc * 32 + quad * 8 + j) * 8192 + rloc];
        pack_hilo(xv, xhi[kc], xlo[kc]);
    }

    // ---- per-lane strength values (channel = nt*16 + l15) for Q/K path ----
    float svq_l[4], sv_l[4];
    #pragma unroll
    for (int nt = 0; nt < 4; ++nt) {
        svq_l[nt] = svq[nt * 16 + l15];
        sv_l[nt]  = sv[nt * 16 + l15];
    }
    // ---- per-reg strength values (channel = mt*16 + quad*4 + rr) for V ----
    f32x4 svA[4];
    #pragma unroll
    for (int mt = 0; mt < 4; ++mt)
        svA[mt] = *(const f32x4*)(sv + mt * 16 + quad * 4);

    // ---- Q/K store geometry: row = r0 + quad*4 + rr ----
    int idxq[4];
    #pragma unroll
    for (int rr = 0; rr < 4; ++rr) {
        const int rl = quad * 4 + rr;
        const int w_ = rl & 7;
        const int s_loc = ((r0 & 8191) >> 3) + (rl >> 3);
        idxq[rr] = (b * 4 + (w_ >> 1)) * 131072 + s_loc * 128 + (w_ & 1) * 64 + l15;
    }

    // ---- V store geometry (lane = row) ----
    const int row_g = r0 + l15;
    const int s_idx = (row_g >> 3) & 1023;
    const int w_idx = row_g & 7;
    const int bh    = b * 4 + (w_idx >> 1);
    const int dbase = (w_idx & 1) * 64;
    unsigned short* vtb = yvt2 + (size_t)bh * 131072 + (s_idx >> 6) * 8192
                        + (size_t)dbase * 64 + (s_idx & 63);

    // ================= Q and K (swapped operands: lane = channel) ==========
    #pragma unroll
    for (int mat = 0; mat < 2; ++mat) {
        const unsigned short* mh = packs + mat * 8192;
        const unsigned short* ml = mh + 4096;
        f32x4 acc[4] = {};
        #pragma unroll
        for (int kc = 0; kc < 2; ++kc)
            #pragma unroll
            for (int nt = 0; nt < 4; ++nt) {
                const int off = (nt * 16 + l15) * 64 + kc * 32 + quad * 8;
                u32x4 ehi = *(const u32x4*)(mh + off);
                u32x4 elo = *(const u32x4*)(ml + off);
                acc[nt] = __builtin_amdgcn_mfma_f32_16x16x32_bf16(
                    __builtin_bit_cast(short8, xhi[kc]),
                    __builtin_bit_cast(short8, ehi), acc[nt], 0, 0, 0);
                acc[nt] = __builtin_amdgcn_mfma_f32_16x16x32_bf16(
                    __builtin_bit_cast(short8, xlo[kc]),
                    __builtin_bit_cast(short8, ehi), acc[nt], 0, 0, 0);
                acc[nt] = __builtin_amdgcn_mfma_f32_16x16x32_bf16(
                    __builtin_bit_cast(short8, xhi[kc]),
                    __builtin_bit_cast(short8, elo), acc[nt], 0, 0, 0);
            }
        unsigned short* y = (mat == 0 ? yqh : ykh);
        const float* svp = (mat == 0 ? svq_l : sv_l);
        #pragma unroll
        for (int nt = 0; nt < 4; ++nt)
            #pragma unroll
            for (int rr = 0; rr < 4; ++rr)
                y[(size_t)idxq[rr] + nt * 16] = f2bf(acc[nt][rr] + svp[nt]);
    }

    // ================= V (original operands: lane = row) ===================
    {
        const unsigned short* mh = packs + 2 * 8192;
        const unsigned short* ml = mh + 4096;
        f32x4 acc[4] = {};
        #pragma unroll
        for (int kc = 0; kc < 2; ++kc)
            #pragma unroll
            for (int mt = 0; mt < 4; ++mt) {
                const int off = (mt * 16 + l15) * 64 + kc * 32 + quad * 8;
                u32x4 ehi = *(const u32x4*)(mh + off);
                u32x4 elo = *(const u32x4*)(ml + off);
                acc[mt] = __builtin_amdgcn_mfma_f32_16x16x32_bf16(
                    __builtin_bit_cast(short8, ehi),
                    __builtin_bit_cast(short8, xhi[kc]), acc[mt], 0, 0, 0);
                acc[mt] = __builtin_amdgcn_mfma_f32_16x16x32_bf16(
                    __builtin_bit_cast(short8, ehi),
                    __builtin_bit_cast(short8, xlo[kc]), acc[mt], 0, 0, 0);
                acc[mt] = __builtin_amdgcn_mfma_f32_16x16x32_bf16(
                    __builtin_bit_cast(short8, elo),
                    __builtin_bit_cast(short8, xhi[kc]), acc[mt], 0, 0, 0);
            }
        #pragma unroll
        for (int mt = 0; mt < 4; ++mt)
            #pragma unroll
            for (int rr = 0; rr < 4; ++rr) {
                const int c = mt * 16 + quad * 4 + rr;
                vtb[(size_t)c * 64] = f2bf(acc[mt][rr] + svA[mt][rr]);
            }
    }
}

// ---------------------------------------------------------------------------
// K2 k_attn: canonical LDS-staged flash attention.
// Grid 512 = 16 bh x 32 q-tiles (32 rows).  Block 4 waves; wave w owns the
// (q-half, d-half) quadrant.  K/V 64-t tiles staged contiguously into padded
// LDS, double-buffered, 1 barrier/tile.  No-max softmax, quad-shuffle P
// transpose, per-lane l.
// ---------------------------------------------------------------------------
__global__ __launch_bounds__(256, 2) void k_attn(
    const unsigned short* __restrict__ yqh, const unsigned short* __restrict__ ykh,
    const unsigned short* __restrict__ yvt2,
    const float* __restrict__ xbar, const float* __restrict__ vw,
    const int* __restrict__ embed_id, const float* __restrict__ sv,
    const float* __restrict__ gate, float* __restrict__ out)
{
    __shared__ __align__(16) unsigned short kx[2][64 * 136];   // [t][128+8]
    __shared__ __align__(16) unsigned short vx[2][128 * 72];   // [d][64+8]
    __shared__ float vbar_s[128];

    const int tid  = threadIdx.x;
    const int w    = tid >> 6;
    const int lane = tid & 63;
    const int quad = lane >> 4;
    const int l15  = lane & 15;
    const int bh = blockIdx.x & 15, qt = blockIdx.x >> 4;
    const int b = bh >> 2, h = bh & 3;
    const int s0 = qt * 32;
    const int qh = w >> 1;        // q-half (16 rows)
    const int dh = w & 1;         // d-half (64 cols)

    const unsigned short* ykb = ykh + (size_t)bh * 131072;
    const unsigned short* yvb = yvt2 + (size_t)bh * 131072;

    // ---- vbar prologue (pos branch, rank-1 reconstruction) ----
    if (tid < 128) {
        const int c = tid & 63, wloc = tid >> 6;
        const float* ver = vw + embed_id[0] * 4096 + c * 64;
        const float* xbr = xbar + (b * 8 + h * 2 + wloc) * 64;
        float a = sv[c];
        #pragma unroll
        for (int j4 = 0; j4 < 16; ++j4) {
            f32x4 e4 = *(const f32x4*)(ver + j4 * 4);
            f32x4 x4 = *(const f32x4*)(xbr + j4 * 4);
            a += e4[0] * x4[0] + e4[1] * x4[1] + e4[2] * x4[2] + e4[3] * x4[3];
        }
        vbar_s[wloc * 64 + c] = a;
    }

    // ---- Q fragments: B[n=q(l15)][k=d(quad*8+j)], kc = 0..3 ----
    u32x4 qf[4];
    #pragma unroll
    for (int kc = 0; kc < 4; ++kc)
        qf[kc] = *(const u32x4*)(yqh + (size_t)bh * 131072
                 + (s0 + qh * 16 + l15) * 128 + kc * 32 + quad * 8);

    // ---- stage tile 0 ----
    #pragma unroll
    for (int r = 0; r < 4; ++r) {
        const int off = r * 2048 + tid * 8;
        *(u32x4*)&kx[0][(off >> 7) * 136 + (off & 127)] =
            *(const u32x4*)(ykb + off);
        *(u32x4*)&vx[0][(off >> 6) * 72 + (off & 63)] =
            *(const u32x4*)(yvb + off);
    }
    __syncthreads();

    f32x4 o[4] = {};
    float lsum = 0.f;
    const int srcA = ((quad & 1) << 5) + l15;

    for (int it = 0; it < 16; ++it) {
        const int cur = it & 1;
        u32x4 kst[4], vst[4];
        const bool pre = (it < 15);
        if (pre) {
            const unsigned short* ksrc = ykb + (it + 1) * 8192;
            const unsigned short* vsrc = yvb + (it + 1) * 8192;
            #pragma unroll
            for (int r = 0; r < 4; ++r)
                kst[r] = *(const u32x4*)(ksrc + r * 2048 + tid * 8);
            #pragma unroll
            for (int r = 0; r < 4; ++r)
                vst[r] = *(const u32x4*)(vsrc + r * 2048 + tid * 8);
        }

        const unsigned short* kxc = kx[cur];
        const unsigned short* vxc = vx[cur];

        #pragma unroll
        for (int th = 0; th < 2; ++th) {
            f32x4 sa0 = {}, sa1 = {};
            #pragma unroll
            for (int kc = 0; kc < 4; ++kc) {
                u32x4 a0 = *(const u32x4*)&kxc[(th * 32 + l15) * 136 + kc * 32 + quad * 8];
                sa0 = __builtin_amdgcn_mfma_f32_16x16x32_bf16(
                    __builtin_bit_cast(short8, a0),
                    __builtin_bit_cast(short8, qf[kc]), sa0, 0, 0, 0);
            }
            #pragma unroll
            for (int kc = 0; kc < 4; ++kc) {
                u32x4 a1 = *(const u32x4*)&kxc[(th * 32 + 16 + l15) * 136 + kc * 32 + quad * 8];
                sa1 = __builtin_amdgcn_mfma_f32_16x16x32_bf16(
                    __builtin_bit_cast(short8, a1),
                    __builtin_bit_cast(short8, qf[kc]), sa1, 0, 0, 0);
            }

            float p0[4], p1[4];
            #pragma unroll
            for (int r = 0; r < 4; ++r) {
                p0[r] = __expf(sa0[r] - SOFT_C);
                p1[r] = __expf(sa1[r] - SOFT_C);
                lsum += p0[r] + p1[r];
            }

            unsigned int pk00 = (unsigned int)f2bf(p0[0]) | ((unsigned int)f2bf(p0[1]) << 16);
            unsigned int pk01 = (unsigned int)f2bf(p0[2]) | ((unsigned int)f2bf(p0[3]) << 16);
            unsigned int pk10 = (unsigned int)f2bf(p1[0]) | ((unsigned int)f2bf(p1[1]) << 16);
            unsigned int pk11 = (unsigned int)f2bf(p1[2]) | ((unsigned int)f2bf(p1[3]) << 16);
            unsigned int sel0 = (quad < 2) ? pk00 : pk10;
            unsigned int sel1 = (quad < 2) ? pk01 : pk11;
            u32x4 pf;
            pf[0] = (unsigned int)__shfl((int)sel0, srcA);
            pf[1] = (unsigned int)__shfl((int)sel1, srcA);
            pf[2] = (unsigned int)__shfl((int)sel0, srcA + 16);
            pf[3] = (unsigned int)__shfl((int)sel1, srcA + 16);

            #pragma unroll
            for (int dt = 0; dt < 4; ++dt) {
                u32x4 vf = *(const u32x4*)&vxc[(dh * 64 + dt * 16 + l15) * 72
                                               + th * 32 + quad * 8];
                o[dt] = __builtin_amdgcn_mfma_f32_16x16x32_bf16(
                    __builtin_bit_cast(short8, vf),
                    __builtin_bit_cast(short8, pf), o[dt], 0, 0, 0);
            }
        }

        if (pre) {
            #pragma unroll
            for (int r = 0; r < 4; ++r) {
                const int off = r * 2048 + tid * 8;
                *(u32x4*)&kx[cur ^ 1][(off >> 7) * 136 + (off & 127)] = kst[r];
            }
            #pragma unroll
            for (int r = 0; r < 4; ++r) {
                const int off = r * 2048 + tid * 8;
                *(u32x4*)&vx[cur ^ 1][(off >> 6) * 72 + (off & 63)] = vst[r];
            }
        }
        __syncthreads();
    }

    // ---- epilogue: fold l across quads (lane = q), normalize, gate ----
    lsum += __shfl_xor(lsum, 16);
    lsum += __shfl_xor(lsum, 32);
    const float gf = 1.f / (1.f + __expf(-gate[h]));
    const float cf = (1.f - gf) / lsum;
    const int row = b * S_ + s0 + qh * 16 + l15;
    #pragma unroll
    for (int dt = 0; dt < 4; ++dt) {
        const int d0 = dh * 64 + dt * 16 + quad * 4;
        f32x4 vb = *(const f32x4*)&vbar_s[d0];
        f32x4 rv;
        #pragma unroll
        for (int j = 0; j < 4; ++j) rv[j] = cf * o[dt][j] + gf * vb[j];
        *(f32x4*)(out + (size_t)row * F_ + h * HD + d0) = rv;
    }
}

// ---------------------------------------------------------------------------
// K3 k_oproj: output projection as MFMA, prepacked out_w hi/lo, in-place.
// ---------------------------------------------------------------------------
__global__ __launch_bounds__(256) void k_oproj(
    float* __restrict__ out, const unsigned short* __restrict__ packs,
    const float* __restrict__ ob)
{
    const int tid  = threadIdx.x;
    const int wv   = tid >> 6;
    const int lane = tid & 63;
    const int quad = lane >> 4;
    const int l15  = lane & 15;
    const int r0   = blockIdx.x * 64 + wv * 16;
    const unsigned short* owh = packs + 3 * 8192;
    const unsigned short* owl = owh + 4096;

    u32x4 bhi[2], blo[2];
    #pragma unroll
    for (int kc = 0; kc < 2; ++kc) {
        const float* src = out + (size_t)(r0 + l15) * 64 + kc * 32 + quad * 8;
        f32x4 y0 = *(const f32x4*)src;
        f32x4 y1 = *(const f32x4*)(src + 4);
        float yv8[8] = {y0[0], y0[1], y0[2], y0[3], y1[0], y1[1], y1[2], y1[3]};
        pack_hilo(yv8, bhi[kc], blo[kc]);
    }

    f32x4 acc[4] = {};
    #pragma unroll
    for (int kc = 0; kc < 2; ++kc)
        #pragma unroll
        for (int mt = 0; mt < 4; ++mt) {
            const int off = (mt * 16 + l15) * 64 + kc * 32 + quad * 8;
            u32x4 ahi = *(const u32x4*)(owh + off);
            u32x4 alo = *(const u32x4*)(owl + off);
            acc[mt] = __builtin_amdgcn_mfma_f32_16x16x32_bf16(
                __builtin_bit_cast(short8, ahi),
                __builtin_bit_cast(short8, bhi[kc]), acc[mt], 0, 0, 0);
            acc[mt] = __builtin_amdgcn_mfma_f32_16x16x32_bf16(
                __builtin_bit_cast(short8, ahi),
                __builtin_bit_cast(short8, blo[kc]), acc[mt], 0, 0, 0);
            acc[mt] = __builtin_amdgcn_mfma_f32_16x16x32_bf16(
                __builtin_bit_cast(short8, alo),
                __builtin_bit_cast(short8, bhi[kc]), acc[mt], 0, 0, 0);
        }

    #pragma unroll
    for (int mt = 0; mt < 4; ++mt) {
        f32x4 bias = *(const f32x4*)(ob + mt * 16 + quad * 4);
        f32x4 v = acc[mt] + bias;
        *(f32x4*)(out + (size_t)(r0 + l15) * 64 + mt * 16 + quad * 4) = v;
    }
}

extern "C" void kernel_launch(void* const* d_in, const int* in_sizes, int n_in,
                              void* d_out, int out_size, void* d_ws, size_t ws_size,
                              hipStream_t stream) {
    (void)in_sizes; (void)n_in; (void)out_size; (void)ws_size;
    const float* x        = (const float*)d_in[0];
    const float* pos      = (const float*)d_in[1];
    const float* strength = (const float*)d_in[2];
    const int*   embed_id = (const int*)d_in[3];
    const float* qw       = (const float*)d_in[4];
    const float* kw       = (const float*)d_in[5];
    const float* vw       = (const float*)d_in[6];
    const float* pw1      = (const float*)d_in[7];
    const float* pb1      = (const float*)d_in[8];
    const float* pw2      = (const float*)d_in[9];
    const float* pb2      = (const float*)d_in[10];
    const float* head_w   = (const float*)d_in[11];
    const float* gate     = (const float*)d_in[13];
    const float* out_w    = (const float*)d_in[14];
    const float* out_b    = (const float*)d_in[15];
    const float* str_w    = (const float*)d_in[16];
    const float* str_b    = (const float*)d_in[17];
    float* out = (float*)d_out;

    unsigned short* yqh   = (unsigned short*)d_ws;         // 4 MiB
    unsigned short* ykh   = yqh + 2097152;                 // 4 MiB
    unsigned short* yvt2  = ykh + 2097152;                 // 4 MiB
    unsigned short* packs = yvt2 + 2097152;                // 8 x 4096 shorts
    float* sv   = (float*)(packs + 8 * 4096);              // 64
    float* svq  = sv + 64;                                 // 64
    float* p_g  = svq + 64;                                // 16384
    float* xbar = p_g + 16384;                             // 2048

    k_prep<<<9, 256, 0, stream>>>(embed_id, qw, kw, vw, out_w, pos,
                                  pw1, pb1, pw2, pb2, head_w,
                                  strength, str_w, str_b, packs, sv, svq, p_g);
    k_qkv<<<768, 256, 0, stream>>>(x, packs, sv, svq, p_g, yqh, ykh, yvt2, xbar);
    k_attn<<<512, 256, 0, stream>>>(yqh, ykh, yvt2, xbar, vw, embed_id, sv,
                                    gate, out);
    k_oproj<<<512, 256, 0, stream>>>(out, packs, out_b);
}